// Round 19
// baseline (146.003 us; speedup 1.0000x reference)
//
#include <hip/hip_runtime.h>
#include <math.h>

#define T_N     4096
#define B_N     64
#define C_N     64
#define NFILT   2
#define F_BINS  2049
#define NPAIRS  2016
#define NFEAT   4032
#define NOUT    4
#define TSG     4
#define NKS     32            // (4096/TSG)/32 K-steps per gram block

#define PI_F 3.14159265358979323846f

typedef _Float16 f16x8 __attribute__((ext_vector_type(8)));
typedef _Float16 f16x2 __attribute__((ext_vector_type(2)));
typedef float    f32x4 __attribute__((ext_vector_type(4)));
typedef float    cplx  __attribute__((ext_vector_type(2)));   // (re, im)

// ---------------------------------------------------------------------------
// Spectrum layout of the 3-phase register FFT (N = 16*16*16):
//   thread t = k1*16 + j1, register q = j2  holds bin k = q*256 + j1*16 + k1.
// Filter: interleaved cplx at p(k) = (k&0xF00) + ((k&15)<<4) + ((k>>4)&15).
//
// r19: fused kernel re-gridded — one block per (b, channel-pair, FILTER)
// (4096 blocks = 16/CU, was 2048 = 8/CU). r18 post-mortem: at 8 blocks/CU
// the barrier-heavy fused kernel sat at 27% occupancy / 55% VALUBusy
// (drain/tail dominated). Forward FFT recomputed per filter (+18% inst,
// r10/r13-proven trade; x reads L2-hot) buys 2x queue depth and half the
// per-block barrier chain. X unpacked to f32 registers (36 VGPR), u written
// directly — no X round-trip, absmax ~4e-3.
// ---------------------------------------------------------------------------

// ---- ws layout (bytes) ----
#define OFF_U     65536
#define G_BYTES   (128 * TSG * 12288 * 4)

// ---------------- filter construction (2 blocks, one per filter) ------------
__global__ __launch_bounds__(256) void filter_kernel(
    const float* __restrict__ fm_, const float* __restrict__ bw_,
    const float* __restrict__ sp_, const float* __restrict__ gd_,
    cplx* __restrict__ filt) {
  __shared__ float smag[F_BINS];
  __shared__ float sred[256];
  const int tid = threadIdx.x;
  const int f = blockIdx.x;
  cplx* Fc = filt + f * 4096;
  for (int p = tid; p < 4096; p += 256) Fc[p] = cplx{0.0f, 0.0f};
  const float fm = fminf(fmaxf(fm_[f], 1.0f / 128.0f), 45.0f / 128.0f);
  const float bw = fminf(fmaxf(bw_[f], 1.0f / 128.0f), 1.0f);
  const float pp = fminf(fmaxf(sp_[f], 2.0f), 3.0f) * 8.0f - 14.0f;
  const float gd = gd_[f];
  const float scale = bw / (2.0f * powf(0.69314718055994531f, 1.0f / pp));
  float lmax = 0.0f;
  for (int i = tid; i < F_BINS; i += 256) {
    const float n = (float)i / 2048.0f;
    const float m = expf(-powf((fabsf(n - fm) + 1e-8f) / scale, pp));
    smag[i] = m;
    lmax = fmaxf(lmax, m);
  }
  sred[tid] = lmax;
  __syncthreads();
  for (int s = 128; s > 0; s >>= 1) {
    if (tid < s) sred[tid] = fmaxf(sred[tid], sred[tid + s]);
    __syncthreads();
  }
  const float inv = 1.0f / sred[0];
  for (int k = tid; k < F_BINS; k += 256) {
    const float m = smag[k] * inv;
    const float pha = -gd * ((float)k * 0.125f) * PI_F;
    float sn, cs;
    sincosf(pha, &sn, &cs);
    const float dcs = (k == 0) ? 1.0f : 2.0f;
    const float sT = dcs * (1.0f / (float)T_N);
    const int p = (k & 0xF00) + ((k & 15) << 4) + ((k >> 4) & 15);
    Fc[p] = cplx{m * cs * sT, m * sn * sT};
  }
}

// ---------------- complex helpers ----------------
__device__ __forceinline__ cplx cmul(cplx a, cplx w) {
  const cplx wx = __builtin_shufflevector(w, w, 0, 0);
  const cplx wy = __builtin_shufflevector(w, w, 1, 1);
  const cplx as = __builtin_shufflevector(a, a, 1, 0);
  return cplx{-as.x, as.y} * wy + a * wx;
}
// a * conj(w)
__device__ __forceinline__ cplx cmulc(cplx a, cplx w) {
  const cplx wx = __builtin_shufflevector(w, w, 0, 0);
  const cplx wy = __builtin_shufflevector(w, w, 1, 1);
  const cplx as = __builtin_shufflevector(a, a, 1, 0);
  return cplx{as.x, -as.y} * wy + a * wx;
}
// e^{i*2pi*rev}, rev in revolutions, |rev| < 1
__device__ __forceinline__ cplx twid(float rev) {
  return cplx{__builtin_amdgcn_cosf(rev), __builtin_amdgcn_sinf(rev)};
}

// ---------------- 16-point DFT, natural order in/out, in registers ----------
template<int SGN>
__device__ __forceinline__ void dft16(cplx* __restrict__ v) {
  const float sg = (float)SGN;
  const float C1 = 0.923879532511287f, S1 = 0.382683432365090f;
  const float Hh = 0.707106781186548f;
  cplx g[16];
#pragma unroll
  for (int n2 = 0; n2 < 4; ++n2) {
    const cplx a = v[n2], b = v[4 + n2], c = v[8 + n2], d = v[12 + n2];
    const cplx t0 = a + c, t1 = a - c, t2 = b + d, t3 = b - d;
    const cplx it3 = (SGN < 0) ? cplx{t3.y, -t3.x} : cplx{-t3.y, t3.x};
    g[n2]      = t0 + t2;
    g[8 + n2]  = t0 - t2;
    g[4 + n2]  = t1 + it3;
    g[12 + n2] = t1 - it3;
  }
  g[5]  = cmul(g[5],  cplx{C1,  sg * S1});
  g[6]  = cmul(g[6],  cplx{Hh,  sg * Hh});
  g[7]  = cmul(g[7],  cplx{S1,  sg * C1});
  g[9]  = cmul(g[9],  cplx{Hh,  sg * Hh});
  g[10] = (SGN < 0) ? cplx{g[10].y, -g[10].x} : cplx{-g[10].y, g[10].x};
  g[11] = cmul(g[11], cplx{-Hh, sg * Hh});
  g[13] = cmul(g[13], cplx{S1,  sg * C1});
  g[14] = cmul(g[14], cplx{-Hh, sg * Hh});
  g[15] = cmul(g[15], cplx{-C1, -sg * S1});
#pragma unroll
  for (int k1 = 0; k1 < 4; ++k1) {
    const cplx a = g[4 * k1], b = g[4 * k1 + 1];
    const cplx c = g[4 * k1 + 2], d = g[4 * k1 + 3];
    const cplx t0 = a + c, t1 = a - c, t2 = b + d, t3 = b - d;
    const cplx it3 = (SGN < 0) ? cplx{t3.y, -t3.x} : cplx{-t3.y, t3.x};
    v[k1]      = t0 + t2;
    v[8 + k1]  = t0 - t2;
    v[4 + k1]  = t1 + it3;
    v[12 + k1] = t1 - it3;
  }
}

// ---- tr_group on 8-row half buffer; caller ensures hlds is free on entry ---
__device__ __forceinline__ void tr_group_half(cplx* __restrict__ v,
                                              cplx* __restrict__ hlds, int t) {
  const int g = t >> 4, j1 = t & 15;
  const int rowb = (g & 7) * 264;
  if (g < 8) {
#pragma unroll
    for (int r = 0; r < 16; ++r)
      hlds[rowb + r * 16 + ((j1 + r) & 15)] = v[r];
  }
  __syncthreads();
  if (g < 8) {
#pragma unroll
    for (int a = 0; a < 16; ++a)
      v[a] = hlds[rowb + j1 * 16 + ((a + j1) & 15)];
  }
  __syncthreads();
  if (g >= 8) {
#pragma unroll
    for (int r = 0; r < 16; ++r)
      hlds[rowb + r * 16 + ((j1 + r) & 15)] = v[r];
  }
  __syncthreads();
  if (g >= 8) {
#pragma unroll
    for (int a = 0; a < 16; ++a)
      v[a] = hlds[rowb + j1 * 16 + ((a + j1) & 15)];
  }
}

// ---- inverse FFT body: filtered one-sided spectrum X[9] -> unit phasors ----
__device__ __forceinline__ void inv_body(
    const cplx* __restrict__ X, const cplx* __restrict__ Fc,
    cplx* __restrict__ hlds, const cplx* __restrict__ TB,
    const cplx* __restrict__ TCB,
    _Float16* __restrict__ upr, _Float16* __restrict__ upi, int t) {
  const int j1 = t & 15;
  const int g  = t >> 4;
  __syncthreads();                             // hlds free of previous readers

  cplx v[16];
#pragma unroll
  for (int q = 0; q < 9; ++q)                  // component-wise filter (pk_mul)
    v[q] = X[q] * Fc[q * 256 + t];
#pragma unroll
  for (int q = 9; q < 16; ++q)
    v[q] = cplx{0.0f, 0.0f};                   // hilbert zero-pad (folds)

  dft16<1>(v);
#pragma unroll
  for (int k = 1; k < 16; ++k)                 // chain B' from LDS table
    v[k] = cmul(v[k], TB[k * 16 + j1]);

  tr_group_half(v, hlds, t);

  dft16<1>(v);
  {
    // chain C: w(m1) = TCB[t] * TB[m1*16+k1]  (TB doubles as step table)
    const cplx tcb = TCB[t];
    v[0] = cmul(v[0], tcb);
#pragma unroll
    for (int m1 = 1; m1 < 16; ++m1) {
      const cplx w = cmul(tcb, TB[m1 * 16 + g]);
      v[m1] = cmul(v[m1], w);
    }
  }

  // ---- tr_cross, half-buffer: logical rows 0-7 then 8-15 ----
  {
    cplx tmp[8];
    const int base = (g & 7) * 264 + j1;
    __syncthreads();                           // hlds free of tr_group readers
    if (g < 8) {
#pragma unroll
      for (int m = 0; m < 16; ++m) hlds[base + m * 16] = v[m];
    }
    __syncthreads();
#pragma unroll
    for (int k = 0; k < 8; ++k) tmp[k] = hlds[k * 264 + t];
    __syncthreads();
    if (g >= 8) {
#pragma unroll
      for (int m = 0; m < 16; ++m) hlds[base + m * 16] = v[m];
    }
    __syncthreads();
#pragma unroll
    for (int k = 0; k < 8; ++k) v[8 + k] = hlds[k * 264 + t];
#pragma unroll
    for (int k = 0; k < 8; ++k) v[k] = tmp[k];
  }

  dft16<1>(v);

#pragma unroll
  for (int n1 = 0; n1 < 16; ++n1) {
    const float ir = rsqrtf(v[n1].x * v[n1].x + v[n1].y * v[n1].y + 1e-6f);
    upr[n1 * 256 + t] = (_Float16)(v[n1].x * ir);
    upi[n1 * 256 + t] = (_Float16)(v[n1].y * ir);
  }
}

// ------ fused: fwd (two-for-one) + unpack + 2x inverse, one filter/block ----
__global__ __launch_bounds__(256) void fused_kernel(
    const float* __restrict__ x, const cplx* __restrict__ filt,
    _Float16* __restrict__ Urg, _Float16* __restrict__ Uig, int chunkbase) {
  const int f  = blockIdx.x & 1;
  const int cp = (blockIdx.x >> 1) & 31;   // channel pair: 2cp, 2cp+1
  const int bb = blockIdx.x >> 6;
  const int b  = chunkbase + bb;
  const int t  = threadIdx.x;
  const int j1 = t & 15;
  const int g  = t >> 4;
  __shared__ cplx hlds[8 * 264];       // 16896 B
  __shared__ cplx TB[256];             // twid(+a*b/256) at [a*16+b]
  __shared__ cplx TCB[256];            // twid(+a*b/4096) at [a*16+b]

  {
    const int prod = g * j1;
    TB[t]  = twid((float)prod * (1.0f / 256.0f));
    TCB[t] = twid((float)prod * (1.0f / 4096.0f));
  }

  cplx v[16];
  const float* xp0 = x + ((size_t)(b * C_N + 2 * cp)) * T_N;
  const float* xp1 = xp0 + T_N;
#pragma unroll
  for (int r = 0; r < 16; ++r)
    v[r] = cplx{xp0[r * 256 + t], xp1[r * 256 + t]};

  dft16<-1>(v);
#pragma unroll
  for (int k = 1; k < 16; ++k)                 // chain A: e^{-2pi i t k/4096}
    v[k] = cmul(v[k], twid((float)(t * k) * (-1.0f / 4096.0f)));

  // ---- tr_cross, half-buffer (fwd orientation, r17-verified) ----
  {
    __syncthreads();                           // covers TB/TCB visibility too
#pragma unroll
    for (int k = 0; k < 8; ++k) hlds[k * 264 + t] = v[k];
    __syncthreads();
    cplx tmp[8];
    if (g < 8) {
      const int base = g * 264 + j1;
#pragma unroll
      for (int m = 0; m < 8; ++m) tmp[m] = hlds[base + (8 + m) * 16];
#pragma unroll
      for (int m = 0; m < 8; ++m) v[m] = hlds[base + m * 16];
    }
    __syncthreads();
#pragma unroll
    for (int k = 0; k < 8; ++k) hlds[k * 264 + t] = v[8 + k];
    __syncthreads();
    if (g < 8) {
#pragma unroll
      for (int m = 0; m < 8; ++m) v[8 + m] = tmp[m];
    } else {
      const int base = (g - 8) * 264 + j1;
#pragma unroll
      for (int m = 0; m < 16; ++m) v[m] = hlds[base + m * 16];
    }
  }

  dft16<-1>(v);
#pragma unroll
  for (int k = 1; k < 16; ++k)                 // chain B: conj of TB
    v[k] = cmulc(v[k], TB[k * 16 + j1]);

  __syncthreads();                             // hlds free of tr_cross readers
  tr_group_half(v, hlds, t);
  dft16<-1>(v);

  // ---- conjugate-symmetry unpack into f32 REGISTERS (two passes) ----
  const int tp = (g == 0) ? ((16 - j1) & 15)
                          : (((16 - g) << 4) | (15 - j1));
  cplx X0[9], X1[9];

  __syncthreads();                             // hlds free of tr_group readers
#pragma unroll
  for (int q = 8; q < 16; ++q) hlds[(q - 8) * 264 + t] = v[q];
  __syncthreads();
#pragma unroll
  for (int q = 0; q < 8; ++q) {                // pass 1: q = 0..7
    const int qp = (t == 0) ? ((16 - q) & 15) : (15 - q);
    const cplx Z  = v[q];
    const cplx Zp = (qp >= 8) ? hlds[(qp - 8) * 264 + tp] : Z;
    X0[q] = cplx{0.5f * (Z.x + Zp.x), 0.5f * (Z.y - Zp.y)};
    X1[q] = cplx{0.5f * (Z.y + Zp.y), 0.5f * (Zp.x - Z.x)};
  }
  __syncthreads();
#pragma unroll
  for (int q = 0; q < 8; ++q) hlds[q * 264 + t] = v[q];
  __syncthreads();
  {                                            // pass 2: q = 8
    const cplx Z  = v[8];
    const cplx Zp = (t == 0) ? Z : hlds[7 * 264 + tp];
    X0[8] = cplx{0.5f * (Z.x + Zp.x), 0.5f * (Z.y - Zp.y)};
    X1[8] = cplx{0.5f * (Z.y + Zp.y), 0.5f * (Zp.x - Z.x)};
  }

  // ---- 2 inverse bodies: (ch0, ch1) for this block's filter ----
  const cplx* Fc = filt + f * 4096;
  const int sl = bb * 2 + f;
  _Float16* upr0 = Urg + ((size_t)sl * C_N + 2 * cp) * T_N;
  _Float16* upi0 = Uig + ((size_t)sl * C_N + 2 * cp) * T_N;
  inv_body(X0, Fc, hlds, TB, TCB, upr0, upi0, t);
  inv_body(X1, Fc, hlds, TB, TCB, upr0 + T_N, upi0 + T_N, t);
}

// ---------------- gram via f16 MFMA -> per-tsplit partial planes ------------
__global__ __launch_bounds__(256) void gram_kernel(
    const _Float16* __restrict__ Urg, const _Float16* __restrict__ Uig,
    float* __restrict__ Gp, int slicebase) {
  const int sl = blockIdx.x / TSG;
  const int ts = blockIdx.x % TSG;
  const int tid = threadIdx.x;
  const int w = tid >> 6;
  const int lane = tid & 63;
  __shared__ _Float16 sUr[2][64 * 40], sUi[2][64 * 40];

  const int row = tid >> 2, quarter = tid & 3;
  const size_t goff = (size_t)sl * C_N * T_N + (size_t)row * T_N
                      + ts * (T_N / TSG) + quarter * 8;
  const int loff = row * 40 + quarter * 8;
  const int frow = (lane & 15) * 40 + (lane >> 4) * 8;
  const int aoff = w * 640 + frow;

  f32x4 accRr[4] = {}, accIi[4] = {}, accRi[4] = {};

  f16x8 rr = *(const f16x8*)&Urg[goff];
  f16x8 ri = *(const f16x8*)&Uig[goff];
  int cur = 0;
  for (int ks = 0; ks < NKS; ++ks) {
    *(f16x8*)&sUr[cur][loff] = rr;
    *(f16x8*)&sUi[cur][loff] = ri;
    if (ks + 1 < NKS) {
      rr = *(const f16x8*)&Urg[goff + (ks + 1) * 32];
      ri = *(const f16x8*)&Uig[goff + (ks + 1) * 32];
    }
    __syncthreads();
    const f16x8 ar = *(const f16x8*)&sUr[cur][aoff];
    const f16x8 ai = *(const f16x8*)&sUi[cur][aoff];
#pragma unroll
    for (int n = 0; n < 4; ++n) {
      const f16x8 br = *(const f16x8*)&sUr[cur][n * 640 + frow];
      const f16x8 bi = *(const f16x8*)&sUi[cur][n * 640 + frow];
      accRr[n] = __builtin_amdgcn_mfma_f32_16x16x32_f16(ar, br, accRr[n], 0, 0, 0);
      accIi[n] = __builtin_amdgcn_mfma_f32_16x16x32_f16(ai, bi, accIi[n], 0, 0, 0);
      accRi[n] = __builtin_amdgcn_mfma_f32_16x16x32_f16(ar, bi, accRi[n], 0, 0, 0);
    }
    cur ^= 1;
  }

  float* Gs = Gp + (size_t)((slicebase + sl) * TSG + ts) * 12288;
  const int r0 = w * 16 + (lane >> 4) * 4;
  const int c0 = lane & 15;
#pragma unroll
  for (int n = 0; n < 4; ++n) {
    const bool upper = (n >= w);   // strictly-below-diagonal Rr/Ii never read
#pragma unroll
    for (int e = 0; e < 4; ++e) {
      const int idx = (r0 + e) * 64 + n * 16 + c0;
      if (upper) {
        Gs[idx] = accRr[n][e];
        Gs[4096 + idx] = accIi[n][e];
      }
      Gs[8192 + idx] = accRi[n][e];
    }
  }
}

// ---------------- PLV (sums TSG partials) + scatter to feature layout -------
__global__ __launch_bounds__(256) void plv_kernel(
    const float* __restrict__ Gp, float* __restrict__ feats) {
  const int idx = blockIdx.x * 256 + threadIdx.x;
  if (idx >= B_N * NFILT * NPAIRS) return;
  const int slice = idx / NPAIRS;
  const int p = idx - slice * NPAIRS;
  const int b = slice >> 1, f = slice & 1;
  const int r = NPAIRS - 1 - p;
  int m = (int)((sqrtf((float)(8 * r + 1)) - 1.0f) * 0.5f);
  while ((m + 1) * (m + 2) / 2 <= r) ++m;
  while (m * (m + 1) / 2 > r) --m;
  const int c = 62 - m;
  const int d = 63 - (r - m * (m + 1) / 2);
  const float* Gs = Gp + (size_t)slice * TSG * 12288;
  float rr = 0, ii = 0, ri = 0, ir = 0;
#pragma unroll
  for (int ts = 0; ts < TSG; ++ts) {
    const float* P = Gs + ts * 12288;
    rr += P[c * 64 + d];
    ii += P[4096 + c * 64 + d];
    ri += P[8192 + c * 64 + d];
    ir += P[8192 + d * 64 + c];
  }
  const float cre = rr + ii;
  const float cim = ri - ir;
  const float plv = sqrtf(cre * cre + cim * cim + 1e-6f) * (1.0f / (float)T_N);
  feats[b * NFEAT + p * NFILT + f] = plv;
}

// ---------------- batch stats (training-mode BN, biased var) ----------------
__global__ __launch_bounds__(64) void stats_kernel(
    const float* __restrict__ feats, float* __restrict__ stats) {
  const int j = blockIdx.x * 64 + threadIdx.x;
  if (j >= NFEAT) return;
  float s = 0.0f;
  for (int b = 0; b < B_N; ++b) s += feats[b * NFEAT + j];
  const float mu = s * (1.0f / (float)B_N);
  float v = 0.0f;
  for (int b = 0; b < B_N; ++b) {
    const float d = feats[b * NFEAT + j] - mu;
    v += d * d;
  }
  v *= (1.0f / (float)B_N);
  stats[j] = mu;
  stats[NFEAT + j] = 1.0f / sqrtf(v + 1e-5f);
}

// ---------------- normalize + linear ----------------
__global__ __launch_bounds__(256) void out_kernel(
    const float* __restrict__ feats, const float* __restrict__ stats,
    const float* __restrict__ w, const float* __restrict__ lb,
    float* __restrict__ out) {
  const int b = blockIdx.x;
  const int tid = threadIdx.x;
  float acc0 = 0, acc1 = 0, acc2 = 0, acc3 = 0;
  for (int j = tid; j < NFEAT; j += 256) {
    const float v = (feats[b * NFEAT + j] - stats[j]) * stats[NFEAT + j];
    acc0 += v * w[0 * NFEAT + j];
    acc1 += v * w[1 * NFEAT + j];
    acc2 += v * w[2 * NFEAT + j];
    acc3 += v * w[3 * NFEAT + j];
  }
  __shared__ float red[4][256];
  red[0][tid] = acc0; red[1][tid] = acc1; red[2][tid] = acc2; red[3][tid] = acc3;
  __syncthreads();
  for (int s = 128; s > 0; s >>= 1) {
    if (tid < s) {
#pragma unroll
      for (int o = 0; o < 4; ++o) red[o][tid] += red[o][tid + s];
    }
    __syncthreads();
  }
  if (tid < 4) out[b * NOUT + tid] = red[tid][0] + lb[tid];
}

extern "C" void kernel_launch(void* const* d_in, const int* in_sizes, int n_in,
                              void* d_out, int out_size, void* d_ws, size_t ws_size,
                              hipStream_t stream) {
  const float* x  = (const float*)d_in[0];
  const float* fm = (const float*)d_in[1];
  const float* bw = (const float*)d_in[2];
  const float* sp = (const float*)d_in[3];
  const float* gd = (const float*)d_in[4];
  const float* lw = (const float*)d_in[5];
  const float* lb = (const float*)d_in[6];
  float* out = (float*)d_out;
  char* base = (char*)d_ws;

  // adaptive batch chunk: largest of {64,32,16} that fits ws
  const size_t perCB = 2 * 1048576;            // u planes only (X stays in regs)
  const size_t fixed = OFF_U + (size_t)G_BYTES + (size_t)B_N * NFEAT * 4 + 2 * NFEAT * 4;
  int CB = 64;
  if (ws_size < fixed + (size_t)64 * perCB) CB = 32;
  if (ws_size < fixed + (size_t)32 * perCB) CB = 16;
  const int nchunk = B_N / CB;

  const size_t u_bytes = (size_t)CB * 1048576;  // per component array
  cplx*     filt  = (cplx*)base;
  _Float16* Urg   = (_Float16*)(base + OFF_U);
  _Float16* Uig   = (_Float16*)(base + OFF_U + u_bytes);
  float*    Gp    = (float*)(base + OFF_U + 2 * u_bytes);
  float*    feats = (float*)(base + OFF_U + 2 * u_bytes + G_BYTES);
  float*    stats = feats + (size_t)B_N * NFEAT;

  filter_kernel<<<NFILT, 256, 0, stream>>>(fm, bw, sp, gd, filt);

  for (int chunk = 0; chunk < nchunk; ++chunk) {
    fused_kernel<<<CB * (C_N / 2) * NFILT, 256, 0, stream>>>(x, filt, Urg, Uig, chunk * CB);
    gram_kernel<<<CB * 2 * TSG, 256, 0, stream>>>(Urg, Uig, Gp, chunk * CB * 2);
  }

  plv_kernel<<<(B_N * NFILT * NPAIRS + 255) / 256, 256, 0, stream>>>(Gp, feats);
  stats_kernel<<<(NFEAT + 63) / 64, 64, 0, stream>>>(feats, stats);
  out_kernel<<<B_N, 256, 0, stream>>>(feats, stats, lw, lb, out);
}

// Round 20
// 133.646 us; speedup vs baseline: 1.0925x; 1.0925x over previous
//
#include <hip/hip_runtime.h>
#include <math.h>

#define T_N     4096
#define B_N     64
#define C_N     64
#define NFILT   2
#define F_BINS  2049
#define NPAIRS  2016
#define NFEAT   4032
#define NOUT    4
#define TSG     4
#define NKS     32            // (4096/TSG)/32 K-steps per gram block

#define PI_F 3.14159265358979323846f

typedef _Float16 f16x8 __attribute__((ext_vector_type(8)));
typedef _Float16 f16x2 __attribute__((ext_vector_type(2)));
typedef float    f32x4 __attribute__((ext_vector_type(4)));
typedef float    cplx  __attribute__((ext_vector_type(2)));   // (re, im)

// ---------------------------------------------------------------------------
// Spectrum layout of the 3-phase register FFT (N = 16*16*16):
//   thread t = k1*16 + j1, register q = j2  holds bin k = q*256 + j1*16 + k1.
// Filter: interleaved cplx at p(k) = (k&0xF00) + ((k&15)<<4) + ((k>>4)&15).
//
// r20 = r18 (best: 134.7us) minus the TCB LDS table:
// r18 post-mortem: grid 2048 = exactly 8 blocks/CU but LDS 20992B caps
// residency at 7 -> batch of 7 + batch of 1 -> 27% avg occupancy. TCB[t] is
// a per-thread CONSTANT used once per inv body -> compute via one twid()
// and keep in 2 VGPRs. LDS 20992 -> 18944 B -> 8 blocks/CU, single batch.
// r19's per-filter re-grid REGRESSED (recomputed fwd +18% inst) — reverted.
// ---------------------------------------------------------------------------

// ---- ws layout (bytes) ----
#define OFF_U     65536
#define G_BYTES   (128 * TSG * 12288 * 4)

// ---------------- filter construction (2 blocks, one per filter) ------------
__global__ __launch_bounds__(256) void filter_kernel(
    const float* __restrict__ fm_, const float* __restrict__ bw_,
    const float* __restrict__ sp_, const float* __restrict__ gd_,
    cplx* __restrict__ filt) {
  __shared__ float smag[F_BINS];
  __shared__ float sred[256];
  const int tid = threadIdx.x;
  const int f = blockIdx.x;
  cplx* Fc = filt + f * 4096;
  for (int p = tid; p < 4096; p += 256) Fc[p] = cplx{0.0f, 0.0f};
  const float fm = fminf(fmaxf(fm_[f], 1.0f / 128.0f), 45.0f / 128.0f);
  const float bw = fminf(fmaxf(bw_[f], 1.0f / 128.0f), 1.0f);
  const float pp = fminf(fmaxf(sp_[f], 2.0f), 3.0f) * 8.0f - 14.0f;
  const float gd = gd_[f];
  const float scale = bw / (2.0f * powf(0.69314718055994531f, 1.0f / pp));
  float lmax = 0.0f;
  for (int i = tid; i < F_BINS; i += 256) {
    const float n = (float)i / 2048.0f;
    const float m = expf(-powf((fabsf(n - fm) + 1e-8f) / scale, pp));
    smag[i] = m;
    lmax = fmaxf(lmax, m);
  }
  sred[tid] = lmax;
  __syncthreads();
  for (int s = 128; s > 0; s >>= 1) {
    if (tid < s) sred[tid] = fmaxf(sred[tid], sred[tid + s]);
    __syncthreads();
  }
  const float inv = 1.0f / sred[0];
  for (int k = tid; k < F_BINS; k += 256) {
    const float m = smag[k] * inv;
    const float pha = -gd * ((float)k * 0.125f) * PI_F;
    float sn, cs;
    sincosf(pha, &sn, &cs);
    const float dcs = (k == 0) ? 1.0f : 2.0f;
    const float sT = dcs * (1.0f / (float)T_N);
    const int p = (k & 0xF00) + ((k & 15) << 4) + ((k >> 4) & 15);
    Fc[p] = cplx{m * cs * sT, m * sn * sT};
  }
}

// ---------------- complex helpers ----------------
__device__ __forceinline__ cplx cmul(cplx a, cplx w) {
  const cplx wx = __builtin_shufflevector(w, w, 0, 0);
  const cplx wy = __builtin_shufflevector(w, w, 1, 1);
  const cplx as = __builtin_shufflevector(a, a, 1, 0);
  return cplx{-as.x, as.y} * wy + a * wx;
}
// a * conj(w)
__device__ __forceinline__ cplx cmulc(cplx a, cplx w) {
  const cplx wx = __builtin_shufflevector(w, w, 0, 0);
  const cplx wy = __builtin_shufflevector(w, w, 1, 1);
  const cplx as = __builtin_shufflevector(a, a, 1, 0);
  return cplx{as.x, -as.y} * wy + a * wx;
}
// e^{i*2pi*rev}, rev in revolutions, |rev| < 1
__device__ __forceinline__ cplx twid(float rev) {
  return cplx{__builtin_amdgcn_cosf(rev), __builtin_amdgcn_sinf(rev)};
}

// ---------------- 16-point DFT, natural order in/out, in registers ----------
template<int SGN>
__device__ __forceinline__ void dft16(cplx* __restrict__ v) {
  const float sg = (float)SGN;
  const float C1 = 0.923879532511287f, S1 = 0.382683432365090f;
  const float Hh = 0.707106781186548f;
  cplx g[16];
#pragma unroll
  for (int n2 = 0; n2 < 4; ++n2) {
    const cplx a = v[n2], b = v[4 + n2], c = v[8 + n2], d = v[12 + n2];
    const cplx t0 = a + c, t1 = a - c, t2 = b + d, t3 = b - d;
    const cplx it3 = (SGN < 0) ? cplx{t3.y, -t3.x} : cplx{-t3.y, t3.x};
    g[n2]      = t0 + t2;
    g[8 + n2]  = t0 - t2;
    g[4 + n2]  = t1 + it3;
    g[12 + n2] = t1 - it3;
  }
  g[5]  = cmul(g[5],  cplx{C1,  sg * S1});
  g[6]  = cmul(g[6],  cplx{Hh,  sg * Hh});
  g[7]  = cmul(g[7],  cplx{S1,  sg * C1});
  g[9]  = cmul(g[9],  cplx{Hh,  sg * Hh});
  g[10] = (SGN < 0) ? cplx{g[10].y, -g[10].x} : cplx{-g[10].y, g[10].x};
  g[11] = cmul(g[11], cplx{-Hh, sg * Hh});
  g[13] = cmul(g[13], cplx{S1,  sg * C1});
  g[14] = cmul(g[14], cplx{-Hh, sg * Hh});
  g[15] = cmul(g[15], cplx{-C1, -sg * S1});
#pragma unroll
  for (int k1 = 0; k1 < 4; ++k1) {
    const cplx a = g[4 * k1], b = g[4 * k1 + 1];
    const cplx c = g[4 * k1 + 2], d = g[4 * k1 + 3];
    const cplx t0 = a + c, t1 = a - c, t2 = b + d, t3 = b - d;
    const cplx it3 = (SGN < 0) ? cplx{t3.y, -t3.x} : cplx{-t3.y, t3.x};
    v[k1]      = t0 + t2;
    v[8 + k1]  = t0 - t2;
    v[4 + k1]  = t1 + it3;
    v[12 + k1] = t1 - it3;
  }
}

// ---- tr_group on 8-row half buffer; caller ensures hlds is free on entry ---
__device__ __forceinline__ void tr_group_half(cplx* __restrict__ v,
                                              cplx* __restrict__ hlds, int t) {
  const int g = t >> 4, j1 = t & 15;
  const int rowb = (g & 7) * 264;
  if (g < 8) {
#pragma unroll
    for (int r = 0; r < 16; ++r)
      hlds[rowb + r * 16 + ((j1 + r) & 15)] = v[r];
  }
  __syncthreads();
  if (g < 8) {
#pragma unroll
    for (int a = 0; a < 16; ++a)
      v[a] = hlds[rowb + j1 * 16 + ((a + j1) & 15)];
  }
  __syncthreads();
  if (g >= 8) {
#pragma unroll
    for (int r = 0; r < 16; ++r)
      hlds[rowb + r * 16 + ((j1 + r) & 15)] = v[r];
  }
  __syncthreads();
  if (g >= 8) {
#pragma unroll
    for (int a = 0; a < 16; ++a)
      v[a] = hlds[rowb + j1 * 16 + ((a + j1) & 15)];
  }
}

// ---- inverse FFT body: filtered one-sided spectrum X[9] -> unit phasors ----
__device__ __forceinline__ void inv_body(
    const cplx* __restrict__ X, const cplx* __restrict__ Fc,
    cplx* __restrict__ hlds, const cplx* __restrict__ TB, cplx tcb,
    _Float16* __restrict__ upr, _Float16* __restrict__ upi, int t) {
  const int j1 = t & 15;
  const int g  = t >> 4;
  __syncthreads();                             // hlds free of previous readers

  cplx v[16];
#pragma unroll
  for (int q = 0; q < 9; ++q)                  // component-wise filter (pk_mul)
    v[q] = X[q] * Fc[q * 256 + t];
#pragma unroll
  for (int q = 9; q < 16; ++q)
    v[q] = cplx{0.0f, 0.0f};                   // hilbert zero-pad (folds)

  dft16<1>(v);
#pragma unroll
  for (int k = 1; k < 16; ++k)                 // chain B' from LDS table
    v[k] = cmul(v[k], TB[k * 16 + j1]);

  tr_group_half(v, hlds, t);

  dft16<1>(v);
  {
    // chain C: w(m1) = tcb * TB[m1*16+k1]  (TB doubles as step table)
    v[0] = cmul(v[0], tcb);
#pragma unroll
    for (int m1 = 1; m1 < 16; ++m1) {
      const cplx w = cmul(tcb, TB[m1 * 16 + g]);
      v[m1] = cmul(v[m1], w);
    }
  }

  // ---- tr_cross, half-buffer: logical rows 0-7 then 8-15 ----
  {
    cplx tmp[8];
    const int base = (g & 7) * 264 + j1;
    __syncthreads();                           // hlds free of tr_group readers
    if (g < 8) {
#pragma unroll
      for (int m = 0; m < 16; ++m) hlds[base + m * 16] = v[m];
    }
    __syncthreads();
#pragma unroll
    for (int k = 0; k < 8; ++k) tmp[k] = hlds[k * 264 + t];
    __syncthreads();
    if (g >= 8) {
#pragma unroll
      for (int m = 0; m < 16; ++m) hlds[base + m * 16] = v[m];
    }
    __syncthreads();
#pragma unroll
    for (int k = 0; k < 8; ++k) v[8 + k] = hlds[k * 264 + t];
#pragma unroll
    for (int k = 0; k < 8; ++k) v[k] = tmp[k];
  }

  dft16<1>(v);

#pragma unroll
  for (int n1 = 0; n1 < 16; ++n1) {
    const float ir = rsqrtf(v[n1].x * v[n1].x + v[n1].y * v[n1].y + 1e-6f);
    upr[n1 * 256 + t] = (_Float16)(v[n1].x * ir);
    upi[n1 * 256 + t] = (_Float16)(v[n1].y * ir);
  }
}

// ---------------- fused: fwd (two-for-one) + unpack + 4x inverse ------------
__global__ __launch_bounds__(256) void fused_kernel(
    const float* __restrict__ x, const cplx* __restrict__ filt,
    _Float16* __restrict__ Urg, _Float16* __restrict__ Uig, int chunkbase) {
  const int cp = blockIdx.x & 31;      // channel pair: channels 2cp, 2cp+1
  const int bb = blockIdx.x >> 5;
  const int b  = chunkbase + bb;
  const int t  = threadIdx.x;
  const int j1 = t & 15;
  const int g  = t >> 4;
  __shared__ cplx hlds[8 * 264];       // 16896 B
  __shared__ cplx TB[256];             // twid(+a*b/256) at [a*16+b]

  TB[t] = twid((float)(g * j1) * (1.0f / 256.0f));
  const cplx tcb = twid((float)(g * j1) * (1.0f / 4096.0f));  // per-thread const

  cplx v[16];
  const float* xp0 = x + ((size_t)(b * C_N + 2 * cp)) * T_N;
  const float* xp1 = xp0 + T_N;
#pragma unroll
  for (int r = 0; r < 16; ++r)
    v[r] = cplx{xp0[r * 256 + t], xp1[r * 256 + t]};

  dft16<-1>(v);
#pragma unroll
  for (int k = 1; k < 16; ++k)                 // chain A: e^{-2pi i t k/4096}
    v[k] = cmul(v[k], twid((float)(t * k) * (-1.0f / 4096.0f)));

  // ---- tr_cross, half-buffer (fwd orientation, r17-verified) ----
  {
    __syncthreads();                           // covers TB visibility too
#pragma unroll
    for (int k = 0; k < 8; ++k) hlds[k * 264 + t] = v[k];
    __syncthreads();
    cplx tmp[8];
    if (g < 8) {
      const int base = g * 264 + j1;
#pragma unroll
      for (int m = 0; m < 8; ++m) tmp[m] = hlds[base + (8 + m) * 16];
#pragma unroll
      for (int m = 0; m < 8; ++m) v[m] = hlds[base + m * 16];
    }
    __syncthreads();
#pragma unroll
    for (int k = 0; k < 8; ++k) hlds[k * 264 + t] = v[8 + k];
    __syncthreads();
    if (g < 8) {
#pragma unroll
      for (int m = 0; m < 8; ++m) v[8 + m] = tmp[m];
    } else {
      const int base = (g - 8) * 264 + j1;
#pragma unroll
      for (int m = 0; m < 16; ++m) v[m] = hlds[base + m * 16];
    }
  }

  dft16<-1>(v);
#pragma unroll
  for (int k = 1; k < 16; ++k)                 // chain B: conj of TB
    v[k] = cmulc(v[k], TB[k * 16 + j1]);

  __syncthreads();                             // hlds free of tr_cross readers
  tr_group_half(v, hlds, t);
  dft16<-1>(v);

  // ---- conjugate-symmetry unpack into f32 REGISTERS (two passes) ----
  const int tp = (g == 0) ? ((16 - j1) & 15)
                          : (((16 - g) << 4) | (15 - j1));
  cplx X0[9], X1[9];

  __syncthreads();                             // hlds free of tr_group readers
#pragma unroll
  for (int q = 8; q < 16; ++q) hlds[(q - 8) * 264 + t] = v[q];
  __syncthreads();
#pragma unroll
  for (int q = 0; q < 8; ++q) {                // pass 1: q = 0..7
    const int qp = (t == 0) ? ((16 - q) & 15) : (15 - q);
    const cplx Z  = v[q];
    const cplx Zp = (qp >= 8) ? hlds[(qp - 8) * 264 + tp] : Z;
    X0[q] = cplx{0.5f * (Z.x + Zp.x), 0.5f * (Z.y - Zp.y)};
    X1[q] = cplx{0.5f * (Z.y + Zp.y), 0.5f * (Zp.x - Z.x)};
  }
  __syncthreads();
#pragma unroll
  for (int q = 0; q < 8; ++q) hlds[q * 264 + t] = v[q];
  __syncthreads();
  {                                            // pass 2: q = 8
    const cplx Z  = v[8];
    const cplx Zp = (t == 0) ? Z : hlds[7 * 264 + tp];
    X0[8] = cplx{0.5f * (Z.x + Zp.x), 0.5f * (Z.y - Zp.y)};
    X1[8] = cplx{0.5f * (Z.y + Zp.y), 0.5f * (Zp.x - Z.x)};
  }

  // ---- 4 inverse bodies: (ch0,ch1) x (f0,f1) ----
  const int c0 = 2 * cp, c1 = 2 * cp + 1;
#pragma unroll 1
  for (int f = 0; f < NFILT; ++f) {
    const cplx* Fc = filt + f * 4096;
    const int sl = bb * 2 + f;
    _Float16* upr0 = Urg + ((size_t)sl * C_N + c0) * T_N;
    _Float16* upi0 = Uig + ((size_t)sl * C_N + c0) * T_N;
    inv_body(X0, Fc, hlds, TB, tcb, upr0, upi0, t);
    _Float16* upr1 = Urg + ((size_t)sl * C_N + c1) * T_N;
    _Float16* upi1 = Uig + ((size_t)sl * C_N + c1) * T_N;
    inv_body(X1, Fc, hlds, TB, tcb, upr1, upi1, t);
  }
}

// ---------------- gram via f16 MFMA -> per-tsplit partial planes ------------
__global__ __launch_bounds__(256) void gram_kernel(
    const _Float16* __restrict__ Urg, const _Float16* __restrict__ Uig,
    float* __restrict__ Gp, int slicebase) {
  const int sl = blockIdx.x / TSG;
  const int ts = blockIdx.x % TSG;
  const int tid = threadIdx.x;
  const int w = tid >> 6;
  const int lane = tid & 63;
  __shared__ _Float16 sUr[2][64 * 40], sUi[2][64 * 40];

  const int row = tid >> 2, quarter = tid & 3;
  const size_t goff = (size_t)sl * C_N * T_N + (size_t)row * T_N
                      + ts * (T_N / TSG) + quarter * 8;
  const int loff = row * 40 + quarter * 8;
  const int frow = (lane & 15) * 40 + (lane >> 4) * 8;
  const int aoff = w * 640 + frow;

  f32x4 accRr[4] = {}, accIi[4] = {}, accRi[4] = {};

  f16x8 rr = *(const f16x8*)&Urg[goff];
  f16x8 ri = *(const f16x8*)&Uig[goff];
  int cur = 0;
  for (int ks = 0; ks < NKS; ++ks) {
    *(f16x8*)&sUr[cur][loff] = rr;
    *(f16x8*)&sUi[cur][loff] = ri;
    if (ks + 1 < NKS) {
      rr = *(const f16x8*)&Urg[goff + (ks + 1) * 32];
      ri = *(const f16x8*)&Uig[goff + (ks + 1) * 32];
    }
    __syncthreads();
    const f16x8 ar = *(const f16x8*)&sUr[cur][aoff];
    const f16x8 ai = *(const f16x8*)&sUi[cur][aoff];
#pragma unroll
    for (int n = 0; n < 4; ++n) {
      const f16x8 br = *(const f16x8*)&sUr[cur][n * 640 + frow];
      const f16x8 bi = *(const f16x8*)&sUi[cur][n * 640 + frow];
      accRr[n] = __builtin_amdgcn_mfma_f32_16x16x32_f16(ar, br, accRr[n], 0, 0, 0);
      accIi[n] = __builtin_amdgcn_mfma_f32_16x16x32_f16(ai, bi, accIi[n], 0, 0, 0);
      accRi[n] = __builtin_amdgcn_mfma_f32_16x16x32_f16(ar, bi, accRi[n], 0, 0, 0);
    }
    cur ^= 1;
  }

  float* Gs = Gp + (size_t)((slicebase + sl) * TSG + ts) * 12288;
  const int r0 = w * 16 + (lane >> 4) * 4;
  const int c0 = lane & 15;
#pragma unroll
  for (int n = 0; n < 4; ++n) {
    const bool upper = (n >= w);   // strictly-below-diagonal Rr/Ii never read
#pragma unroll
    for (int e = 0; e < 4; ++e) {
      const int idx = (r0 + e) * 64 + n * 16 + c0;
      if (upper) {
        Gs[idx] = accRr[n][e];
        Gs[4096 + idx] = accIi[n][e];
      }
      Gs[8192 + idx] = accRi[n][e];
    }
  }
}

// ---------------- PLV (sums TSG partials) + scatter to feature layout -------
__global__ __launch_bounds__(256) void plv_kernel(
    const float* __restrict__ Gp, float* __restrict__ feats) {
  const int idx = blockIdx.x * 256 + threadIdx.x;
  if (idx >= B_N * NFILT * NPAIRS) return;
  const int slice = idx / NPAIRS;
  const int p = idx - slice * NPAIRS;
  const int b = slice >> 1, f = slice & 1;
  const int r = NPAIRS - 1 - p;
  int m = (int)((sqrtf((float)(8 * r + 1)) - 1.0f) * 0.5f);
  while ((m + 1) * (m + 2) / 2 <= r) ++m;
  while (m * (m + 1) / 2 > r) --m;
  const int c = 62 - m;
  const int d = 63 - (r - m * (m + 1) / 2);
  const float* Gs = Gp + (size_t)slice * TSG * 12288;
  float rr = 0, ii = 0, ri = 0, ir = 0;
#pragma unroll
  for (int ts = 0; ts < TSG; ++ts) {
    const float* P = Gs + ts * 12288;
    rr += P[c * 64 + d];
    ii += P[4096 + c * 64 + d];
    ri += P[8192 + c * 64 + d];
    ir += P[8192 + d * 64 + c];
  }
  const float cre = rr + ii;
  const float cim = ri - ir;
  const float plv = sqrtf(cre * cre + cim * cim + 1e-6f) * (1.0f / (float)T_N);
  feats[b * NFEAT + p * NFILT + f] = plv;
}

// ---------------- batch stats (training-mode BN, biased var) ----------------
__global__ __launch_bounds__(64) void stats_kernel(
    const float* __restrict__ feats, float* __restrict__ stats) {
  const int j = blockIdx.x * 64 + threadIdx.x;
  if (j >= NFEAT) return;
  float s = 0.0f;
  for (int b = 0; b < B_N; ++b) s += feats[b * NFEAT + j];
  const float mu = s * (1.0f / (float)B_N);
  float v = 0.0f;
  for (int b = 0; b < B_N; ++b) {
    const float d = feats[b * NFEAT + j] - mu;
    v += d * d;
  }
  v *= (1.0f / (float)B_N);
  stats[j] = mu;
  stats[NFEAT + j] = 1.0f / sqrtf(v + 1e-5f);
}

// ---------------- normalize + linear ----------------
__global__ __launch_bounds__(256) void out_kernel(
    const float* __restrict__ feats, const float* __restrict__ stats,
    const float* __restrict__ w, const float* __restrict__ lb,
    float* __restrict__ out) {
  const int b = blockIdx.x;
  const int tid = threadIdx.x;
  float acc0 = 0, acc1 = 0, acc2 = 0, acc3 = 0;
  for (int j = tid; j < NFEAT; j += 256) {
    const float v = (feats[b * NFEAT + j] - stats[j]) * stats[NFEAT + j];
    acc0 += v * w[0 * NFEAT + j];
    acc1 += v * w[1 * NFEAT + j];
    acc2 += v * w[2 * NFEAT + j];
    acc3 += v * w[3 * NFEAT + j];
  }
  __shared__ float red[4][256];
  red[0][tid] = acc0; red[1][tid] = acc1; red[2][tid] = acc2; red[3][tid] = acc3;
  __syncthreads();
  for (int s = 128; s > 0; s >>= 1) {
    if (tid < s) {
#pragma unroll
      for (int o = 0; o < 4; ++o) red[o][tid] += red[o][tid + s];
    }
    __syncthreads();
  }
  if (tid < 4) out[b * NOUT + tid] = red[tid][0] + lb[tid];
}

extern "C" void kernel_launch(void* const* d_in, const int* in_sizes, int n_in,
                              void* d_out, int out_size, void* d_ws, size_t ws_size,
                              hipStream_t stream) {
  const float* x  = (const float*)d_in[0];
  const float* fm = (const float*)d_in[1];
  const float* bw = (const float*)d_in[2];
  const float* sp = (const float*)d_in[3];
  const float* gd = (const float*)d_in[4];
  const float* lw = (const float*)d_in[5];
  const float* lb = (const float*)d_in[6];
  float* out = (float*)d_out;
  char* base = (char*)d_ws;

  // adaptive batch chunk: largest of {64,32,16} that fits ws
  const size_t perCB = 2 * 1048576;            // u planes only (X stays in regs)
  const size_t fixed = OFF_U + (size_t)G_BYTES + (size_t)B_N * NFEAT * 4 + 2 * NFEAT * 4;
  int CB = 64;
  if (ws_size < fixed + (size_t)64 * perCB) CB = 32;
  if (ws_size < fixed + (size_t)32 * perCB) CB = 16;
  const int nchunk = B_N / CB;

  const size_t u_bytes = (size_t)CB * 1048576;  // per component array
  cplx*     filt  = (cplx*)base;
  _Float16* Urg   = (_Float16*)(base + OFF_U);
  _Float16* Uig   = (_Float16*)(base + OFF_U + u_bytes);
  float*    Gp    = (float*)(base + OFF_U + 2 * u_bytes);
  float*    feats = (float*)(base + OFF_U + 2 * u_bytes + G_BYTES);
  float*    stats = feats + (size_t)B_N * NFEAT;

  filter_kernel<<<NFILT, 256, 0, stream>>>(fm, bw, sp, gd, filt);

  for (int chunk = 0; chunk < nchunk; ++chunk) {
    fused_kernel<<<CB * (C_N / 2), 256, 0, stream>>>(x, filt, Urg, Uig, chunk * CB);
    gram_kernel<<<CB * 2 * TSG, 256, 0, stream>>>(Urg, Uig, Gp, chunk * CB * 2);
  }

  plv_kernel<<<(B_N * NFILT * NPAIRS + 255) / 256, 256, 0, stream>>>(Gp, feats);
  stats_kernel<<<(NFEAT + 63) / 64, 64, 0, stream>>>(feats, stats);
  out_kernel<<<B_N, 256, 0, stream>>>(feats, stats, lw, lb, out);
}

// Round 21
// 133.584 us; speedup vs baseline: 1.0930x; 1.0005x over previous
//
#include <hip/hip_runtime.h>
#include <math.h>

#define T_N     4096
#define B_N     64
#define C_N     64
#define NFILT   2
#define F_BINS  2049
#define NPAIRS  2016
#define NFEAT   4032
#define NOUT    4
#define TSG     4
#define NKS     32            // (4096/TSG)/32 K-steps per gram block

#define PI_F 3.14159265358979323846f

typedef _Float16 f16x8 __attribute__((ext_vector_type(8)));
typedef _Float16 f16x2 __attribute__((ext_vector_type(2)));
typedef float    f32x4 __attribute__((ext_vector_type(4)));
typedef float    cplx  __attribute__((ext_vector_type(2)));   // (re, im)

// ---------------------------------------------------------------------------
// Spectrum layout of the 3-phase register FFT (N = 16*16*16):
//   thread t = k1*16 + j1, register q = j2  holds bin k = q*256 + j1*16 + k1.
// Filter: interleaved cplx at p(k) = (k&0xF00) + ((k&15)<<4) + ((k>>4)&15).
//
// r21 = r20 with the unpacked spectrum X0/X1 held as f16x2 (18 VGPRs instead
// of 36 f32). r20 post-mortem: occupancy stayed 27% because VGPR=72 is in
// the 4-waves/SIMD class (halves at 64 — m69); LDS was no longer the cap.
// Packing X under the 64-VGPR cliff targets 8 blocks/CU (LDS 18944*8 fits).
// f16-X precision = r8-r17 configuration (absmax 0.0156, 3.5x under thr).
// ---------------------------------------------------------------------------

// ---- ws layout (bytes) ----
#define OFF_U     65536
#define G_BYTES   (128 * TSG * 12288 * 4)

// ---------------- filter construction (2 blocks, one per filter) ------------
__global__ __launch_bounds__(256) void filter_kernel(
    const float* __restrict__ fm_, const float* __restrict__ bw_,
    const float* __restrict__ sp_, const float* __restrict__ gd_,
    cplx* __restrict__ filt) {
  __shared__ float smag[F_BINS];
  __shared__ float sred[256];
  const int tid = threadIdx.x;
  const int f = blockIdx.x;
  cplx* Fc = filt + f * 4096;
  for (int p = tid; p < 4096; p += 256) Fc[p] = cplx{0.0f, 0.0f};
  const float fm = fminf(fmaxf(fm_[f], 1.0f / 128.0f), 45.0f / 128.0f);
  const float bw = fminf(fmaxf(bw_[f], 1.0f / 128.0f), 1.0f);
  const float pp = fminf(fmaxf(sp_[f], 2.0f), 3.0f) * 8.0f - 14.0f;
  const float gd = gd_[f];
  const float scale = bw / (2.0f * powf(0.69314718055994531f, 1.0f / pp));
  float lmax = 0.0f;
  for (int i = tid; i < F_BINS; i += 256) {
    const float n = (float)i / 2048.0f;
    const float m = expf(-powf((fabsf(n - fm) + 1e-8f) / scale, pp));
    smag[i] = m;
    lmax = fmaxf(lmax, m);
  }
  sred[tid] = lmax;
  __syncthreads();
  for (int s = 128; s > 0; s >>= 1) {
    if (tid < s) sred[tid] = fmaxf(sred[tid], sred[tid + s]);
    __syncthreads();
  }
  const float inv = 1.0f / sred[0];
  for (int k = tid; k < F_BINS; k += 256) {
    const float m = smag[k] * inv;
    const float pha = -gd * ((float)k * 0.125f) * PI_F;
    float sn, cs;
    sincosf(pha, &sn, &cs);
    const float dcs = (k == 0) ? 1.0f : 2.0f;
    const float sT = dcs * (1.0f / (float)T_N);
    const int p = (k & 0xF00) + ((k & 15) << 4) + ((k >> 4) & 15);
    Fc[p] = cplx{m * cs * sT, m * sn * sT};
  }
}

// ---------------- complex helpers ----------------
__device__ __forceinline__ cplx cmul(cplx a, cplx w) {
  const cplx wx = __builtin_shufflevector(w, w, 0, 0);
  const cplx wy = __builtin_shufflevector(w, w, 1, 1);
  const cplx as = __builtin_shufflevector(a, a, 1, 0);
  return cplx{-as.x, as.y} * wy + a * wx;
}
// a * conj(w)
__device__ __forceinline__ cplx cmulc(cplx a, cplx w) {
  const cplx wx = __builtin_shufflevector(w, w, 0, 0);
  const cplx wy = __builtin_shufflevector(w, w, 1, 1);
  const cplx as = __builtin_shufflevector(a, a, 1, 0);
  return cplx{as.x, -as.y} * wy + a * wx;
}
// e^{i*2pi*rev}, rev in revolutions, |rev| < 1
__device__ __forceinline__ cplx twid(float rev) {
  return cplx{__builtin_amdgcn_cosf(rev), __builtin_amdgcn_sinf(rev)};
}

// ---------------- 16-point DFT, natural order in/out, in registers ----------
template<int SGN>
__device__ __forceinline__ void dft16(cplx* __restrict__ v) {
  const float sg = (float)SGN;
  const float C1 = 0.923879532511287f, S1 = 0.382683432365090f;
  const float Hh = 0.707106781186548f;
  cplx g[16];
#pragma unroll
  for (int n2 = 0; n2 < 4; ++n2) {
    const cplx a = v[n2], b = v[4 + n2], c = v[8 + n2], d = v[12 + n2];
    const cplx t0 = a + c, t1 = a - c, t2 = b + d, t3 = b - d;
    const cplx it3 = (SGN < 0) ? cplx{t3.y, -t3.x} : cplx{-t3.y, t3.x};
    g[n2]      = t0 + t2;
    g[8 + n2]  = t0 - t2;
    g[4 + n2]  = t1 + it3;
    g[12 + n2] = t1 - it3;
  }
  g[5]  = cmul(g[5],  cplx{C1,  sg * S1});
  g[6]  = cmul(g[6],  cplx{Hh,  sg * Hh});
  g[7]  = cmul(g[7],  cplx{S1,  sg * C1});
  g[9]  = cmul(g[9],  cplx{Hh,  sg * Hh});
  g[10] = (SGN < 0) ? cplx{g[10].y, -g[10].x} : cplx{-g[10].y, g[10].x};
  g[11] = cmul(g[11], cplx{-Hh, sg * Hh});
  g[13] = cmul(g[13], cplx{S1,  sg * C1});
  g[14] = cmul(g[14], cplx{-Hh, sg * Hh});
  g[15] = cmul(g[15], cplx{-C1, -sg * S1});
#pragma unroll
  for (int k1 = 0; k1 < 4; ++k1) {
    const cplx a = g[4 * k1], b = g[4 * k1 + 1];
    const cplx c = g[4 * k1 + 2], d = g[4 * k1 + 3];
    const cplx t0 = a + c, t1 = a - c, t2 = b + d, t3 = b - d;
    const cplx it3 = (SGN < 0) ? cplx{t3.y, -t3.x} : cplx{-t3.y, t3.x};
    v[k1]      = t0 + t2;
    v[8 + k1]  = t0 - t2;
    v[4 + k1]  = t1 + it3;
    v[12 + k1] = t1 - it3;
  }
}

// ---- tr_group on 8-row half buffer; caller ensures hlds is free on entry ---
__device__ __forceinline__ void tr_group_half(cplx* __restrict__ v,
                                              cplx* __restrict__ hlds, int t) {
  const int g = t >> 4, j1 = t & 15;
  const int rowb = (g & 7) * 264;
  if (g < 8) {
#pragma unroll
    for (int r = 0; r < 16; ++r)
      hlds[rowb + r * 16 + ((j1 + r) & 15)] = v[r];
  }
  __syncthreads();
  if (g < 8) {
#pragma unroll
    for (int a = 0; a < 16; ++a)
      v[a] = hlds[rowb + j1 * 16 + ((a + j1) & 15)];
  }
  __syncthreads();
  if (g >= 8) {
#pragma unroll
    for (int r = 0; r < 16; ++r)
      hlds[rowb + r * 16 + ((j1 + r) & 15)] = v[r];
  }
  __syncthreads();
  if (g >= 8) {
#pragma unroll
    for (int a = 0; a < 16; ++a)
      v[a] = hlds[rowb + j1 * 16 + ((a + j1) & 15)];
  }
}

// ---- inverse FFT body: filtered one-sided spectrum X[9] (f16x2) -> u -------
__device__ __forceinline__ void inv_body(
    const f16x2* __restrict__ X, const cplx* __restrict__ Fc,
    cplx* __restrict__ hlds, const cplx* __restrict__ TB, cplx tcb,
    _Float16* __restrict__ upr, _Float16* __restrict__ upi, int t) {
  const int j1 = t & 15;
  const int g  = t >> 4;
  __syncthreads();                             // hlds free of previous readers

  cplx v[16];
#pragma unroll
  for (int q = 0; q < 9; ++q)                  // component-wise filter (pk_mul)
    v[q] = cplx{(float)X[q][0], (float)X[q][1]} * Fc[q * 256 + t];
#pragma unroll
  for (int q = 9; q < 16; ++q)
    v[q] = cplx{0.0f, 0.0f};                   // hilbert zero-pad (folds)

  dft16<1>(v);
#pragma unroll
  for (int k = 1; k < 16; ++k)                 // chain B' from LDS table
    v[k] = cmul(v[k], TB[k * 16 + j1]);

  tr_group_half(v, hlds, t);

  dft16<1>(v);
  {
    // chain C: w(m1) = tcb * TB[m1*16+k1]  (TB doubles as step table)
    v[0] = cmul(v[0], tcb);
#pragma unroll
    for (int m1 = 1; m1 < 16; ++m1) {
      const cplx w = cmul(tcb, TB[m1 * 16 + g]);
      v[m1] = cmul(v[m1], w);
    }
  }

  // ---- tr_cross, half-buffer: logical rows 0-7 then 8-15 ----
  {
    cplx tmp[8];
    const int base = (g & 7) * 264 + j1;
    __syncthreads();                           // hlds free of tr_group readers
    if (g < 8) {
#pragma unroll
      for (int m = 0; m < 16; ++m) hlds[base + m * 16] = v[m];
    }
    __syncthreads();
#pragma unroll
    for (int k = 0; k < 8; ++k) tmp[k] = hlds[k * 264 + t];
    __syncthreads();
    if (g >= 8) {
#pragma unroll
      for (int m = 0; m < 16; ++m) hlds[base + m * 16] = v[m];
    }
    __syncthreads();
#pragma unroll
    for (int k = 0; k < 8; ++k) v[8 + k] = hlds[k * 264 + t];
#pragma unroll
    for (int k = 0; k < 8; ++k) v[k] = tmp[k];
  }

  dft16<1>(v);

#pragma unroll
  for (int n1 = 0; n1 < 16; ++n1) {
    const float ir = rsqrtf(v[n1].x * v[n1].x + v[n1].y * v[n1].y + 1e-6f);
    upr[n1 * 256 + t] = (_Float16)(v[n1].x * ir);
    upi[n1 * 256 + t] = (_Float16)(v[n1].y * ir);
  }
}

// ---------------- fused: fwd (two-for-one) + unpack + 4x inverse ------------
__global__ __launch_bounds__(256) void fused_kernel(
    const float* __restrict__ x, const cplx* __restrict__ filt,
    _Float16* __restrict__ Urg, _Float16* __restrict__ Uig, int chunkbase) {
  const int cp = blockIdx.x & 31;      // channel pair: channels 2cp, 2cp+1
  const int bb = blockIdx.x >> 5;
  const int b  = chunkbase + bb;
  const int t  = threadIdx.x;
  const int j1 = t & 15;
  const int g  = t >> 4;
  __shared__ cplx hlds[8 * 264];       // 16896 B
  __shared__ cplx TB[256];             // twid(+a*b/256) at [a*16+b]

  TB[t] = twid((float)(g * j1) * (1.0f / 256.0f));
  const cplx tcb = twid((float)(g * j1) * (1.0f / 4096.0f));  // per-thread const

  cplx v[16];
  const float* xp0 = x + ((size_t)(b * C_N + 2 * cp)) * T_N;
  const float* xp1 = xp0 + T_N;
#pragma unroll
  for (int r = 0; r < 16; ++r)
    v[r] = cplx{xp0[r * 256 + t], xp1[r * 256 + t]};

  dft16<-1>(v);
#pragma unroll
  for (int k = 1; k < 16; ++k)                 // chain A: e^{-2pi i t k/4096}
    v[k] = cmul(v[k], twid((float)(t * k) * (-1.0f / 4096.0f)));

  // ---- tr_cross, half-buffer (fwd orientation, r17-verified) ----
  {
    __syncthreads();                           // covers TB visibility too
#pragma unroll
    for (int k = 0; k < 8; ++k) hlds[k * 264 + t] = v[k];
    __syncthreads();
    cplx tmp[8];
    if (g < 8) {
      const int base = g * 264 + j1;
#pragma unroll
      for (int m = 0; m < 8; ++m) tmp[m] = hlds[base + (8 + m) * 16];
#pragma unroll
      for (int m = 0; m < 8; ++m) v[m] = hlds[base + m * 16];
    }
    __syncthreads();
#pragma unroll
    for (int k = 0; k < 8; ++k) hlds[k * 264 + t] = v[8 + k];
    __syncthreads();
    if (g < 8) {
#pragma unroll
      for (int m = 0; m < 8; ++m) v[8 + m] = tmp[m];
    } else {
      const int base = (g - 8) * 264 + j1;
#pragma unroll
      for (int m = 0; m < 16; ++m) v[m] = hlds[base + m * 16];
    }
  }

  dft16<-1>(v);
#pragma unroll
  for (int k = 1; k < 16; ++k)                 // chain B: conj of TB
    v[k] = cmulc(v[k], TB[k * 16 + j1]);

  __syncthreads();                             // hlds free of tr_cross readers
  tr_group_half(v, hlds, t);
  dft16<-1>(v);

  // ---- conjugate-symmetry unpack -> f16x2 registers (18 VGPR not 36) ----
  const int tp = (g == 0) ? ((16 - j1) & 15)
                          : (((16 - g) << 4) | (15 - j1));
  f16x2 X0[9], X1[9];

  __syncthreads();                             // hlds free of tr_group readers
#pragma unroll
  for (int q = 8; q < 16; ++q) hlds[(q - 8) * 264 + t] = v[q];
  __syncthreads();
#pragma unroll
  for (int q = 0; q < 8; ++q) {                // pass 1: q = 0..7
    const int qp = (t == 0) ? ((16 - q) & 15) : (15 - q);
    const cplx Z  = v[q];
    const cplx Zp = (qp >= 8) ? hlds[(qp - 8) * 264 + tp] : Z;
    X0[q] = f16x2{(_Float16)(0.5f * (Z.x + Zp.x)),
                  (_Float16)(0.5f * (Z.y - Zp.y))};
    X1[q] = f16x2{(_Float16)(0.5f * (Z.y + Zp.y)),
                  (_Float16)(0.5f * (Zp.x - Z.x))};
  }
  __syncthreads();
#pragma unroll
  for (int q = 0; q < 8; ++q) hlds[q * 264 + t] = v[q];
  __syncthreads();
  {                                            // pass 2: q = 8
    const cplx Z  = v[8];
    const cplx Zp = (t == 0) ? Z : hlds[7 * 264 + tp];
    X0[8] = f16x2{(_Float16)(0.5f * (Z.x + Zp.x)),
                  (_Float16)(0.5f * (Z.y - Zp.y))};
    X1[8] = f16x2{(_Float16)(0.5f * (Z.y + Zp.y)),
                  (_Float16)(0.5f * (Zp.x - Z.x))};
  }

  // ---- 4 inverse bodies: (ch0,ch1) x (f0,f1) ----
  const int c0 = 2 * cp, c1 = 2 * cp + 1;
#pragma unroll 1
  for (int f = 0; f < NFILT; ++f) {
    const cplx* Fc = filt + f * 4096;
    const int sl = bb * 2 + f;
    _Float16* upr0 = Urg + ((size_t)sl * C_N + c0) * T_N;
    _Float16* upi0 = Uig + ((size_t)sl * C_N + c0) * T_N;
    inv_body(X0, Fc, hlds, TB, tcb, upr0, upi0, t);
    _Float16* upr1 = Urg + ((size_t)sl * C_N + c1) * T_N;
    _Float16* upi1 = Uig + ((size_t)sl * C_N + c1) * T_N;
    inv_body(X1, Fc, hlds, TB, tcb, upr1, upi1, t);
  }
}

// ---------------- gram via f16 MFMA -> per-tsplit partial planes ------------
__global__ __launch_bounds__(256) void gram_kernel(
    const _Float16* __restrict__ Urg, const _Float16* __restrict__ Uig,
    float* __restrict__ Gp, int slicebase) {
  const int sl = blockIdx.x / TSG;
  const int ts = blockIdx.x % TSG;
  const int tid = threadIdx.x;
  const int w = tid >> 6;
  const int lane = tid & 63;
  __shared__ _Float16 sUr[2][64 * 40], sUi[2][64 * 40];

  const int row = tid >> 2, quarter = tid & 3;
  const size_t goff = (size_t)sl * C_N * T_N + (size_t)row * T_N
                      + ts * (T_N / TSG) + quarter * 8;
  const int loff = row * 40 + quarter * 8;
  const int frow = (lane & 15) * 40 + (lane >> 4) * 8;
  const int aoff = w * 640 + frow;

  f32x4 accRr[4] = {}, accIi[4] = {}, accRi[4] = {};

  f16x8 rr = *(const f16x8*)&Urg[goff];
  f16x8 ri = *(const f16x8*)&Uig[goff];
  int cur = 0;
  for (int ks = 0; ks < NKS; ++ks) {
    *(f16x8*)&sUr[cur][loff] = rr;
    *(f16x8*)&sUi[cur][loff] = ri;
    if (ks + 1 < NKS) {
      rr = *(const f16x8*)&Urg[goff + (ks + 1) * 32];
      ri = *(const f16x8*)&Uig[goff + (ks + 1) * 32];
    }
    __syncthreads();
    const f16x8 ar = *(const f16x8*)&sUr[cur][aoff];
    const f16x8 ai = *(const f16x8*)&sUi[cur][aoff];
#pragma unroll
    for (int n = 0; n < 4; ++n) {
      const f16x8 br = *(const f16x8*)&sUr[cur][n * 640 + frow];
      const f16x8 bi = *(const f16x8*)&sUi[cur][n * 640 + frow];
      accRr[n] = __builtin_amdgcn_mfma_f32_16x16x32_f16(ar, br, accRr[n], 0, 0, 0);
      accIi[n] = __builtin_amdgcn_mfma_f32_16x16x32_f16(ai, bi, accIi[n], 0, 0, 0);
      accRi[n] = __builtin_amdgcn_mfma_f32_16x16x32_f16(ar, bi, accRi[n], 0, 0, 0);
    }
    cur ^= 1;
  }

  float* Gs = Gp + (size_t)((slicebase + sl) * TSG + ts) * 12288;
  const int r0 = w * 16 + (lane >> 4) * 4;
  const int c0 = lane & 15;
#pragma unroll
  for (int n = 0; n < 4; ++n) {
    const bool upper = (n >= w);   // strictly-below-diagonal Rr/Ii never read
#pragma unroll
    for (int e = 0; e < 4; ++e) {
      const int idx = (r0 + e) * 64 + n * 16 + c0;
      if (upper) {
        Gs[idx] = accRr[n][e];
        Gs[4096 + idx] = accIi[n][e];
      }
      Gs[8192 + idx] = accRi[n][e];
    }
  }
}

// ---------------- PLV (sums TSG partials) + scatter to feature layout -------
__global__ __launch_bounds__(256) void plv_kernel(
    const float* __restrict__ Gp, float* __restrict__ feats) {
  const int idx = blockIdx.x * 256 + threadIdx.x;
  if (idx >= B_N * NFILT * NPAIRS) return;
  const int slice = idx / NPAIRS;
  const int p = idx - slice * NPAIRS;
  const int b = slice >> 1, f = slice & 1;
  const int r = NPAIRS - 1 - p;
  int m = (int)((sqrtf((float)(8 * r + 1)) - 1.0f) * 0.5f);
  while ((m + 1) * (m + 2) / 2 <= r) ++m;
  while (m * (m + 1) / 2 > r) --m;
  const int c = 62 - m;
  const int d = 63 - (r - m * (m + 1) / 2);
  const float* Gs = Gp + (size_t)slice * TSG * 12288;
  float rr = 0, ii = 0, ri = 0, ir = 0;
#pragma unroll
  for (int ts = 0; ts < TSG; ++ts) {
    const float* P = Gs + ts * 12288;
    rr += P[c * 64 + d];
    ii += P[4096 + c * 64 + d];
    ri += P[8192 + c * 64 + d];
    ir += P[8192 + d * 64 + c];
  }
  const float cre = rr + ii;
  const float cim = ri - ir;
  const float plv = sqrtf(cre * cre + cim * cim + 1e-6f) * (1.0f / (float)T_N);
  feats[b * NFEAT + p * NFILT + f] = plv;
}

// ---------------- batch stats (training-mode BN, biased var) ----------------
__global__ __launch_bounds__(64) void stats_kernel(
    const float* __restrict__ feats, float* __restrict__ stats) {
  const int j = blockIdx.x * 64 + threadIdx.x;
  if (j >= NFEAT) return;
  float s = 0.0f;
  for (int b = 0; b < B_N; ++b) s += feats[b * NFEAT + j];
  const float mu = s * (1.0f / (float)B_N);
  float v = 0.0f;
  for (int b = 0; b < B_N; ++b) {
    const float d = feats[b * NFEAT + j] - mu;
    v += d * d;
  }
  v *= (1.0f / (float)B_N);
  stats[j] = mu;
  stats[NFEAT + j] = 1.0f / sqrtf(v + 1e-5f);
}

// ---------------- normalize + linear ----------------
__global__ __launch_bounds__(256) void out_kernel(
    const float* __restrict__ feats, const float* __restrict__ stats,
    const float* __restrict__ w, const float* __restrict__ lb,
    float* __restrict__ out) {
  const int b = blockIdx.x;
  const int tid = threadIdx.x;
  float acc0 = 0, acc1 = 0, acc2 = 0, acc3 = 0;
  for (int j = tid; j < NFEAT; j += 256) {
    const float v = (feats[b * NFEAT + j] - stats[j]) * stats[NFEAT + j];
    acc0 += v * w[0 * NFEAT + j];
    acc1 += v * w[1 * NFEAT + j];
    acc2 += v * w[2 * NFEAT + j];
    acc3 += v * w[3 * NFEAT + j];
  }
  __shared__ float red[4][256];
  red[0][tid] = acc0; red[1][tid] = acc1; red[2][tid] = acc2; red[3][tid] = acc3;
  __syncthreads();
  for (int s = 128; s > 0; s >>= 1) {
    if (tid < s) {
#pragma unroll
      for (int o = 0; o < 4; ++o) red[o][tid] += red[o][tid + s];
    }
    __syncthreads();
  }
  if (tid < 4) out[b * NOUT + tid] = red[tid][0] + lb[tid];
}

extern "C" void kernel_launch(void* const* d_in, const int* in_sizes, int n_in,
                              void* d_out, int out_size, void* d_ws, size_t ws_size,
                              hipStream_t stream) {
  const float* x  = (const float*)d_in[0];
  const float* fm = (const float*)d_in[1];
  const float* bw = (const float*)d_in[2];
  const float* sp = (const float*)d_in[3];
  const float* gd = (const float*)d_in[4];
  const float* lw = (const float*)d_in[5];
  const float* lb = (const float*)d_in[6];
  float* out = (float*)d_out;
  char* base = (char*)d_ws;

  // adaptive batch chunk: largest of {64,32,16} that fits ws
  const size_t perCB = 2 * 1048576;            // u planes only (X stays in regs)
  const size_t fixed = OFF_U + (size_t)G_BYTES + (size_t)B_N * NFEAT * 4 + 2 * NFEAT * 4;
  int CB = 64;
  if (ws_size < fixed + (size_t)64 * perCB) CB = 32;
  if (ws_size < fixed + (size_t)32 * perCB) CB = 16;
  const int nchunk = B_N / CB;

  const size_t u_bytes = (size_t)CB * 1048576;  // per component array
  cplx*     filt  = (cplx*)base;
  _Float16* Urg   = (_Float16*)(base + OFF_U);
  _Float16* Uig   = (_Float16*)(base + OFF_U + u_bytes);
  float*    Gp    = (float*)(base + OFF_U + 2 * u_bytes);
  float*    feats = (float*)(base + OFF_U + 2 * u_bytes + G_BYTES);
  float*    stats = feats + (size_t)B_N * NFEAT;

  filter_kernel<<<NFILT, 256, 0, stream>>>(fm, bw, sp, gd, filt);

  for (int chunk = 0; chunk < nchunk; ++chunk) {
    fused_kernel<<<CB * (C_N / 2), 256, 0, stream>>>(x, filt, Urg, Uig, chunk * CB);
    gram_kernel<<<CB * 2 * TSG, 256, 0, stream>>>(Urg, Uig, Gp, chunk * CB * 2);
  }

  plv_kernel<<<(B_N * NFILT * NPAIRS + 255) / 256, 256, 0, stream>>>(Gp, feats);
  stats_kernel<<<(NFEAT + 63) / 64, 64, 0, stream>>>(feats, stats);
  out_kernel<<<B_N, 256, 0, stream>>>(feats, stats, lw, lb, out);
}

// Round 22
// 131.997 us; speedup vs baseline: 1.1061x; 1.0120x over previous
//
#include <hip/hip_runtime.h>
#include <math.h>

#define T_N     4096
#define B_N     64
#define C_N     64
#define NFILT   2
#define F_BINS  2049
#define NPAIRS  2016
#define NFEAT   4032
#define NOUT    4
#define TSG     4
#define NKS     32            // (4096/TSG)/32 K-steps per gram block

#define PI_F 3.14159265358979323846f

typedef _Float16 f16x8 __attribute__((ext_vector_type(8)));
typedef _Float16 f16x2 __attribute__((ext_vector_type(2)));
typedef float    f32x4 __attribute__((ext_vector_type(4)));
typedef float    cplx  __attribute__((ext_vector_type(2)));   // (re, im)

// ---------------------------------------------------------------------------
// Spectrum layout of the 3-phase register FFT (N = 16*16*16):
//   thread t = k1*16 + j1, register q = j2  holds bin k = q*256 + j1*16 + k1.
// Filter: interleaved cplx at p(k) = (k&0xF00) + ((k&15)<<4) + ((k>>4)&15).
//
// r22: fused kernel reverted to FULL 16-row transpose buffers.
// r21 post-mortem: X-packing didn't move VGPR (72->72) => the allocator peak
// is in the transpose phases (v[16]+tmp[8]). At VGPR 72 residency is 4
// blocks/CU for ANY LDS <= 40KB, so the half-buffer machinery (tmp[8],
// exec-mask branches, ~45 barriers/block) is pure overhead in the fused
// kernel. Full buffers (r13-r15-verified): LDS 35840B (still 4 blocks/CU),
// ~22 barriers/block, no tmp moves, single-pass unpack, X back to f32
// (absmax 0.0039).
// ---------------------------------------------------------------------------

// ---- ws layout (bytes) ----
#define OFF_U     65536
#define G_BYTES   (128 * TSG * 12288 * 4)

// ---------------- filter construction (2 blocks, one per filter) ------------
__global__ __launch_bounds__(256) void filter_kernel(
    const float* __restrict__ fm_, const float* __restrict__ bw_,
    const float* __restrict__ sp_, const float* __restrict__ gd_,
    cplx* __restrict__ filt) {
  __shared__ float smag[F_BINS];
  __shared__ float sred[256];
  const int tid = threadIdx.x;
  const int f = blockIdx.x;
  cplx* Fc = filt + f * 4096;
  for (int p = tid; p < 4096; p += 256) Fc[p] = cplx{0.0f, 0.0f};
  const float fm = fminf(fmaxf(fm_[f], 1.0f / 128.0f), 45.0f / 128.0f);
  const float bw = fminf(fmaxf(bw_[f], 1.0f / 128.0f), 1.0f);
  const float pp = fminf(fmaxf(sp_[f], 2.0f), 3.0f) * 8.0f - 14.0f;
  const float gd = gd_[f];
  const float scale = bw / (2.0f * powf(0.69314718055994531f, 1.0f / pp));
  float lmax = 0.0f;
  for (int i = tid; i < F_BINS; i += 256) {
    const float n = (float)i / 2048.0f;
    const float m = expf(-powf((fabsf(n - fm) + 1e-8f) / scale, pp));
    smag[i] = m;
    lmax = fmaxf(lmax, m);
  }
  sred[tid] = lmax;
  __syncthreads();
  for (int s = 128; s > 0; s >>= 1) {
    if (tid < s) sred[tid] = fmaxf(sred[tid], sred[tid + s]);
    __syncthreads();
  }
  const float inv = 1.0f / sred[0];
  for (int k = tid; k < F_BINS; k += 256) {
    const float m = smag[k] * inv;
    const float pha = -gd * ((float)k * 0.125f) * PI_F;
    float sn, cs;
    sincosf(pha, &sn, &cs);
    const float dcs = (k == 0) ? 1.0f : 2.0f;
    const float sT = dcs * (1.0f / (float)T_N);
    const int p = (k & 0xF00) + ((k & 15) << 4) + ((k >> 4) & 15);
    Fc[p] = cplx{m * cs * sT, m * sn * sT};
  }
}

// ---------------- complex helpers ----------------
__device__ __forceinline__ cplx cmul(cplx a, cplx w) {
  const cplx wx = __builtin_shufflevector(w, w, 0, 0);
  const cplx wy = __builtin_shufflevector(w, w, 1, 1);
  const cplx as = __builtin_shufflevector(a, a, 1, 0);
  return cplx{-as.x, as.y} * wy + a * wx;
}
// a * conj(w)
__device__ __forceinline__ cplx cmulc(cplx a, cplx w) {
  const cplx wx = __builtin_shufflevector(w, w, 0, 0);
  const cplx wy = __builtin_shufflevector(w, w, 1, 1);
  const cplx as = __builtin_shufflevector(a, a, 1, 0);
  return cplx{as.x, -as.y} * wy + a * wx;
}
// e^{i*2pi*rev}, rev in revolutions, |rev| < 1
__device__ __forceinline__ cplx twid(float rev) {
  return cplx{__builtin_amdgcn_cosf(rev), __builtin_amdgcn_sinf(rev)};
}

// ---------------- 16-point DFT, natural order in/out, in registers ----------
template<int SGN>
__device__ __forceinline__ void dft16(cplx* __restrict__ v) {
  const float sg = (float)SGN;
  const float C1 = 0.923879532511287f, S1 = 0.382683432365090f;
  const float Hh = 0.707106781186548f;
  cplx g[16];
#pragma unroll
  for (int n2 = 0; n2 < 4; ++n2) {
    const cplx a = v[n2], b = v[4 + n2], c = v[8 + n2], d = v[12 + n2];
    const cplx t0 = a + c, t1 = a - c, t2 = b + d, t3 = b - d;
    const cplx it3 = (SGN < 0) ? cplx{t3.y, -t3.x} : cplx{-t3.y, t3.x};
    g[n2]      = t0 + t2;
    g[8 + n2]  = t0 - t2;
    g[4 + n2]  = t1 + it3;
    g[12 + n2] = t1 - it3;
  }
  g[5]  = cmul(g[5],  cplx{C1,  sg * S1});
  g[6]  = cmul(g[6],  cplx{Hh,  sg * Hh});
  g[7]  = cmul(g[7],  cplx{S1,  sg * C1});
  g[9]  = cmul(g[9],  cplx{Hh,  sg * Hh});
  g[10] = (SGN < 0) ? cplx{g[10].y, -g[10].x} : cplx{-g[10].y, g[10].x};
  g[11] = cmul(g[11], cplx{-Hh, sg * Hh});
  g[13] = cmul(g[13], cplx{S1,  sg * C1});
  g[14] = cmul(g[14], cplx{-Hh, sg * Hh});
  g[15] = cmul(g[15], cplx{-C1, -sg * S1});
#pragma unroll
  for (int k1 = 0; k1 < 4; ++k1) {
    const cplx a = g[4 * k1], b = g[4 * k1 + 1];
    const cplx c = g[4 * k1 + 2], d = g[4 * k1 + 3];
    const cplx t0 = a + c, t1 = a - c, t2 = b + d, t3 = b - d;
    const cplx it3 = (SGN < 0) ? cplx{t3.y, -t3.x} : cplx{-t3.y, t3.x};
    v[k1]      = t0 + t2;
    v[8 + k1]  = t0 - t2;
    v[4 + k1]  = t1 + it3;
    v[12 + k1] = t1 - it3;
  }
}

// full-buffer transposes (r13-r15-verified; stride 264 -> ~2-way banks)
__device__ __forceinline__ void tr_cross_fwd(cplx* __restrict__ v,
                                             cplx* __restrict__ lds, int t) {
  __syncthreads();
#pragma unroll
  for (int k = 0; k < 16; ++k) lds[k * 264 + t] = v[k];
  __syncthreads();
  const int base = (t >> 4) * 264 + (t & 15);
#pragma unroll
  for (int m = 0; m < 16; ++m) v[m] = lds[base + m * 16];
}
__device__ __forceinline__ void tr_cross_inv(cplx* __restrict__ v,
                                             cplx* __restrict__ lds, int t) {
  __syncthreads();
  const int base = (t >> 4) * 264 + (t & 15);
#pragma unroll
  for (int m = 0; m < 16; ++m) lds[base + m * 16] = v[m];
  __syncthreads();
#pragma unroll
  for (int k = 0; k < 16; ++k) v[k] = lds[k * 264 + t];
}
__device__ __forceinline__ void tr_group(cplx* __restrict__ v,
                                         cplx* __restrict__ lds, int t) {
  __syncthreads();
  const int k1 = t >> 4, s = t & 15;
  const int rowb = k1 * 264;
#pragma unroll
  for (int r = 0; r < 16; ++r)
    lds[rowb + r * 16 + ((s + r) & 15)] = v[r];
  __syncthreads();
#pragma unroll
  for (int a = 0; a < 16; ++a)
    v[a] = lds[rowb + s * 16 + ((a + s) & 15)];
}

// ---- inverse FFT body: filtered one-sided spectrum X[9] (f32) -> u ---------
__device__ __forceinline__ void inv_body(
    const cplx* __restrict__ X, const cplx* __restrict__ Fc,
    cplx* __restrict__ lds, const cplx* __restrict__ TB, cplx tcb,
    _Float16* __restrict__ upr, _Float16* __restrict__ upi, int t) {
  const int j1 = t & 15;
  const int g  = t >> 4;

  cplx v[16];
#pragma unroll
  for (int q = 0; q < 9; ++q)                  // component-wise filter (pk_mul)
    v[q] = X[q] * Fc[q * 256 + t];
#pragma unroll
  for (int q = 9; q < 16; ++q)
    v[q] = cplx{0.0f, 0.0f};                   // hilbert zero-pad (folds)

  dft16<1>(v);
#pragma unroll
  for (int k = 1; k < 16; ++k)                 // chain B' from LDS table
    v[k] = cmul(v[k], TB[k * 16 + j1]);

  tr_group(v, lds, t);                         // leading sync orders prev reads

  dft16<1>(v);
  {
    // chain C: w(m1) = tcb * TB[m1*16+k1]  (TB doubles as step table)
    v[0] = cmul(v[0], tcb);
#pragma unroll
    for (int m1 = 1; m1 < 16; ++m1) {
      const cplx w = cmul(tcb, TB[m1 * 16 + g]);
      v[m1] = cmul(v[m1], w);
    }
  }

  tr_cross_inv(v, lds, t);
  dft16<1>(v);

#pragma unroll
  for (int n1 = 0; n1 < 16; ++n1) {
    const float ir = rsqrtf(v[n1].x * v[n1].x + v[n1].y * v[n1].y + 1e-6f);
    upr[n1 * 256 + t] = (_Float16)(v[n1].x * ir);
    upi[n1 * 256 + t] = (_Float16)(v[n1].y * ir);
  }
}

// ---------------- fused: fwd (two-for-one) + unpack + 4x inverse ------------
__global__ __launch_bounds__(256) void fused_kernel(
    const float* __restrict__ x, const cplx* __restrict__ filt,
    _Float16* __restrict__ Urg, _Float16* __restrict__ Uig, int chunkbase) {
  const int cp = blockIdx.x & 31;      // channel pair: channels 2cp, 2cp+1
  const int bb = blockIdx.x >> 5;
  const int b  = chunkbase + bb;
  const int t  = threadIdx.x;
  const int j1 = t & 15;
  const int g  = t >> 4;
  __shared__ cplx lds[16 * 264];       // 33792 B full transpose buffer
  __shared__ cplx TB[256];             // twid(+a*b/256) at [a*16+b]

  TB[t] = twid((float)(g * j1) * (1.0f / 256.0f));
  const cplx tcb = twid((float)(g * j1) * (1.0f / 4096.0f));  // per-thread const

  cplx v[16];
  const float* xp0 = x + ((size_t)(b * C_N + 2 * cp)) * T_N;
  const float* xp1 = xp0 + T_N;
#pragma unroll
  for (int r = 0; r < 16; ++r)
    v[r] = cplx{xp0[r * 256 + t], xp1[r * 256 + t]};

  dft16<-1>(v);
#pragma unroll
  for (int k = 1; k < 16; ++k)                 // chain A: e^{-2pi i t k/4096}
    v[k] = cmul(v[k], twid((float)(t * k) * (-1.0f / 4096.0f)));

  tr_cross_fwd(v, lds, t);                     // leading sync covers TB too

  dft16<-1>(v);
#pragma unroll
  for (int k = 1; k < 16; ++k)                 // chain B: conj of TB
    v[k] = cmulc(v[k], TB[k * 16 + j1]);

  tr_group(v, lds, t);
  dft16<-1>(v);

  // ---- conjugate-symmetry unpack -> f32 registers (single pass) ----
  // partner: tp = (k1==0) ? ((16-j1)&15) : ((16-k1)<<4 | (15-j1));
  //          qp = (t==0) ? ((16-q)&15) : (15-q)   (self-pairs read own slot)
  const int tp = (g == 0) ? ((16 - j1) & 15)
                          : (((16 - g) << 4) | (15 - j1));
  cplx X0[9], X1[9];

  __syncthreads();                             // lds free of tr_group readers
#pragma unroll
  for (int q = 0; q < 16; ++q) lds[q * 264 + t] = v[q];
  __syncthreads();
#pragma unroll
  for (int q = 0; q < 9; ++q) {
    const int qp = (t == 0) ? ((16 - q) & 15) : (15 - q);
    const cplx Z  = v[q];
    const cplx Zp = lds[qp * 264 + tp];
    X0[q] = cplx{0.5f * (Z.x + Zp.x), 0.5f * (Z.y - Zp.y)};
    X1[q] = cplx{0.5f * (Z.y + Zp.y), 0.5f * (Zp.x - Z.x)};
  }

  // ---- 4 inverse bodies: (ch0,ch1) x (f0,f1) ----
  const int c0 = 2 * cp, c1 = 2 * cp + 1;
#pragma unroll 1
  for (int f = 0; f < NFILT; ++f) {
    const cplx* Fc = filt + f * 4096;
    const int sl = bb * 2 + f;
    _Float16* upr0 = Urg + ((size_t)sl * C_N + c0) * T_N;
    _Float16* upi0 = Uig + ((size_t)sl * C_N + c0) * T_N;
    inv_body(X0, Fc, lds, TB, tcb, upr0, upi0, t);
    _Float16* upr1 = Urg + ((size_t)sl * C_N + c1) * T_N;
    _Float16* upi1 = Uig + ((size_t)sl * C_N + c1) * T_N;
    inv_body(X1, Fc, lds, TB, tcb, upr1, upi1, t);
  }
}

// ---------------- gram via f16 MFMA -> per-tsplit partial planes ------------
__global__ __launch_bounds__(256) void gram_kernel(
    const _Float16* __restrict__ Urg, const _Float16* __restrict__ Uig,
    float* __restrict__ Gp, int slicebase) {
  const int sl = blockIdx.x / TSG;
  const int ts = blockIdx.x % TSG;
  const int tid = threadIdx.x;
  const int w = tid >> 6;
  const int lane = tid & 63;
  __shared__ _Float16 sUr[2][64 * 40], sUi[2][64 * 40];

  const int row = tid >> 2, quarter = tid & 3;
  const size_t goff = (size_t)sl * C_N * T_N + (size_t)row * T_N
                      + ts * (T_N / TSG) + quarter * 8;
  const int loff = row * 40 + quarter * 8;
  const int frow = (lane & 15) * 40 + (lane >> 4) * 8;
  const int aoff = w * 640 + frow;

  f32x4 accRr[4] = {}, accIi[4] = {}, accRi[4] = {};

  f16x8 rr = *(const f16x8*)&Urg[goff];
  f16x8 ri = *(const f16x8*)&Uig[goff];
  int cur = 0;
  for (int ks = 0; ks < NKS; ++ks) {
    *(f16x8*)&sUr[cur][loff] = rr;
    *(f16x8*)&sUi[cur][loff] = ri;
    if (ks + 1 < NKS) {
      rr = *(const f16x8*)&Urg[goff + (ks + 1) * 32];
      ri = *(const f16x8*)&Uig[goff + (ks + 1) * 32];
    }
    __syncthreads();
    const f16x8 ar = *(const f16x8*)&sUr[cur][aoff];
    const f16x8 ai = *(const f16x8*)&sUi[cur][aoff];
#pragma unroll
    for (int n = 0; n < 4; ++n) {
      const f16x8 br = *(const f16x8*)&sUr[cur][n * 640 + frow];
      const f16x8 bi = *(const f16x8*)&sUi[cur][n * 640 + frow];
      accRr[n] = __builtin_amdgcn_mfma_f32_16x16x32_f16(ar, br, accRr[n], 0, 0, 0);
      accIi[n] = __builtin_amdgcn_mfma_f32_16x16x32_f16(ai, bi, accIi[n], 0, 0, 0);
      accRi[n] = __builtin_amdgcn_mfma_f32_16x16x32_f16(ar, bi, accRi[n], 0, 0, 0);
    }
    cur ^= 1;
  }

  float* Gs = Gp + (size_t)((slicebase + sl) * TSG + ts) * 12288;
  const int r0 = w * 16 + (lane >> 4) * 4;
  const int c0 = lane & 15;
#pragma unroll
  for (int n = 0; n < 4; ++n) {
    const bool upper = (n >= w);   // strictly-below-diagonal Rr/Ii never read
#pragma unroll
    for (int e = 0; e < 4; ++e) {
      const int idx = (r0 + e) * 64 + n * 16 + c0;
      if (upper) {
        Gs[idx] = accRr[n][e];
        Gs[4096 + idx] = accIi[n][e];
      }
      Gs[8192 + idx] = accRi[n][e];
    }
  }
}

// ---------------- PLV (sums TSG partials) + scatter to feature layout -------
__global__ __launch_bounds__(256) void plv_kernel(
    const float* __restrict__ Gp, float* __restrict__ feats) {
  const int idx = blockIdx.x * 256 + threadIdx.x;
  if (idx >= B_N * NFILT * NPAIRS) return;
  const int slice = idx / NPAIRS;
  const int p = idx - slice * NPAIRS;
  const int b = slice >> 1, f = slice & 1;
  const int r = NPAIRS - 1 - p;
  int m = (int)((sqrtf((float)(8 * r + 1)) - 1.0f) * 0.5f);
  while ((m + 1) * (m + 2) / 2 <= r) ++m;
  while (m * (m + 1) / 2 > r) --m;
  const int c = 62 - m;
  const int d = 63 - (r - m * (m + 1) / 2);
  const float* Gs = Gp + (size_t)slice * TSG * 12288;
  float rr = 0, ii = 0, ri = 0, ir = 0;
#pragma unroll
  for (int ts = 0; ts < TSG; ++ts) {
    const float* P = Gs + ts * 12288;
    rr += P[c * 64 + d];
    ii += P[4096 + c * 64 + d];
    ri += P[8192 + c * 64 + d];
    ir += P[8192 + d * 64 + c];
  }
  const float cre = rr + ii;
  const float cim = ri - ir;
  const float plv = sqrtf(cre * cre + cim * cim + 1e-6f) * (1.0f / (float)T_N);
  feats[b * NFEAT + p * NFILT + f] = plv;
}

// ---------------- batch stats (training-mode BN, biased var) ----------------
__global__ __launch_bounds__(64) void stats_kernel(
    const float* __restrict__ feats, float* __restrict__ stats) {
  const int j = blockIdx.x * 64 + threadIdx.x;
  if (j >= NFEAT) return;
  float s = 0.0f;
  for (int b = 0; b < B_N; ++b) s += feats[b * NFEAT + j];
  const float mu = s * (1.0f / (float)B_N);
  float v = 0.0f;
  for (int b = 0; b < B_N; ++b) {
    const float d = feats[b * NFEAT + j] - mu;
    v += d * d;
  }
  v *= (1.0f / (float)B_N);
  stats[j] = mu;
  stats[NFEAT + j] = 1.0f / sqrtf(v + 1e-5f);
}

// ---------------- normalize + linear ----------------
__global__ __launch_bounds__(256) void out_kernel(
    const float* __restrict__ feats, const float* __restrict__ stats,
    const float* __restrict__ w, const float* __restrict__ lb,
    float* __restrict__ out) {
  const int b = blockIdx.x;
  const int tid = threadIdx.x;
  float acc0 = 0, acc1 = 0, acc2 = 0, acc3 = 0;
  for (int j = tid; j < NFEAT; j += 256) {
    const float v = (feats[b * NFEAT + j] - stats[j]) * stats[NFEAT + j];
    acc0 += v * w[0 * NFEAT + j];
    acc1 += v * w[1 * NFEAT + j];
    acc2 += v * w[2 * NFEAT + j];
    acc3 += v * w[3 * NFEAT + j];
  }
  __shared__ float red[4][256];
  red[0][tid] = acc0; red[1][tid] = acc1; red[2][tid] = acc2; red[3][tid] = acc3;
  __syncthreads();
  for (int s = 128; s > 0; s >>= 1) {
    if (tid < s) {
#pragma unroll
      for (int o = 0; o < 4; ++o) red[o][tid] += red[o][tid + s];
    }
    __syncthreads();
  }
  if (tid < 4) out[b * NOUT + tid] = red[tid][0] + lb[tid];
}

extern "C" void kernel_launch(void* const* d_in, const int* in_sizes, int n_in,
                              void* d_out, int out_size, void* d_ws, size_t ws_size,
                              hipStream_t stream) {
  const float* x  = (const float*)d_in[0];
  const float* fm = (const float*)d_in[1];
  const float* bw = (const float*)d_in[2];
  const float* sp = (const float*)d_in[3];
  const float* gd = (const float*)d_in[4];
  const float* lw = (const float*)d_in[5];
  const float* lb = (const float*)d_in[6];
  float* out = (float*)d_out;
  char* base = (char*)d_ws;

  // adaptive batch chunk: largest of {64,32,16} that fits ws
  const size_t perCB = 2 * 1048576;            // u planes only (X stays in regs)
  const size_t fixed = OFF_U + (size_t)G_BYTES + (size_t)B_N * NFEAT * 4 + 2 * NFEAT * 4;
  int CB = 64;
  if (ws_size < fixed + (size_t)64 * perCB) CB = 32;
  if (ws_size < fixed + (size_t)32 * perCB) CB = 16;
  const int nchunk = B_N / CB;

  const size_t u_bytes = (size_t)CB * 1048576;  // per component array
  cplx*     filt  = (cplx*)base;
  _Float16* Urg   = (_Float16*)(base + OFF_U);
  _Float16* Uig   = (_Float16*)(base + OFF_U + u_bytes);
  float*    Gp    = (float*)(base + OFF_U + 2 * u_bytes);
  float*    feats = (float*)(base + OFF_U + 2 * u_bytes + G_BYTES);
  float*    stats = feats + (size_t)B_N * NFEAT;

  filter_kernel<<<NFILT, 256, 0, stream>>>(fm, bw, sp, gd, filt);

  for (int chunk = 0; chunk < nchunk; ++chunk) {
    fused_kernel<<<CB * (C_N / 2), 256, 0, stream>>>(x, filt, Urg, Uig, chunk * CB);
    gram_kernel<<<CB * 2 * TSG, 256, 0, stream>>>(Urg, Uig, Gp, chunk * CB * 2);
  }

  plv_kernel<<<(B_N * NFILT * NPAIRS + 255) / 256, 256, 0, stream>>>(Gp, feats);
  stats_kernel<<<(NFEAT + 63) / 64, 64, 0, stream>>>(feats, stats);
  out_kernel<<<B_N, 256, 0, stream>>>(feats, stats, lw, lb, out);
}

// Round 24
// 131.695 us; speedup vs baseline: 1.1087x; 1.0023x over previous
//
#include <hip/hip_runtime.h>
#include <math.h>

#define T_N     4096
#define B_N     64
#define C_N     64
#define NFILT   2
#define F_BINS  2049
#define NPAIRS  2016
#define NFEAT   4032
#define NOUT    4
#define TSG     4
#define NKS     32            // (4096/TSG)/32 K-steps per gram block

#define PI_F 3.14159265358979323846f

typedef _Float16 f16x8 __attribute__((ext_vector_type(8)));
typedef _Float16 f16x2 __attribute__((ext_vector_type(2)));
typedef float    f32x4 __attribute__((ext_vector_type(4)));
typedef float    cplx  __attribute__((ext_vector_type(2)));   // (re, im)

// ---------------------------------------------------------------------------
// Spectrum layout of the 3-phase register FFT (N = 16*16*16):
//   thread t = k1*16 + j1, register q = j2  holds bin k = q*256 + j1*16 + k1.
// Filter: interleaved cplx at p(k) = (k&0xF00) + ((k&15)<<4) + ((k>>4)&15).
//
// r24 = r22 verbatim (verified best: 132.0us, absmax 0.0039).
// r23's fused/gram co-dispatch pipeline FAILED correctness (absmax 0.215)
// with no identifiable race mechanism after full re-derivation — reverted.
// Plateau: fused ~91us (barrier-lockstep VALU-bound, VGPR=72 -> 4 blocks/CU;
// occupancy attributes spill per r4/r9), gram ~21us (HBM floor), tails ~12us.
// ---------------------------------------------------------------------------

// ---- ws layout (bytes) ----
#define OFF_U     65536
#define G_BYTES   (128 * TSG * 12288 * 4)

// ---------------- filter construction (2 blocks, one per filter) ------------
__global__ __launch_bounds__(256) void filter_kernel(
    const float* __restrict__ fm_, const float* __restrict__ bw_,
    const float* __restrict__ sp_, const float* __restrict__ gd_,
    cplx* __restrict__ filt) {
  __shared__ float smag[F_BINS];
  __shared__ float sred[256];
  const int tid = threadIdx.x;
  const int f = blockIdx.x;
  cplx* Fc = filt + f * 4096;
  for (int p = tid; p < 4096; p += 256) Fc[p] = cplx{0.0f, 0.0f};
  const float fm = fminf(fmaxf(fm_[f], 1.0f / 128.0f), 45.0f / 128.0f);
  const float bw = fminf(fmaxf(bw_[f], 1.0f / 128.0f), 1.0f);
  const float pp = fminf(fmaxf(sp_[f], 2.0f), 3.0f) * 8.0f - 14.0f;
  const float gd = gd_[f];
  const float scale = bw / (2.0f * powf(0.69314718055994531f, 1.0f / pp));
  float lmax = 0.0f;
  for (int i = tid; i < F_BINS; i += 256) {
    const float n = (float)i / 2048.0f;
    const float m = expf(-powf((fabsf(n - fm) + 1e-8f) / scale, pp));
    smag[i] = m;
    lmax = fmaxf(lmax, m);
  }
  sred[tid] = lmax;
  __syncthreads();
  for (int s = 128; s > 0; s >>= 1) {
    if (tid < s) sred[tid] = fmaxf(sred[tid], sred[tid + s]);
    __syncthreads();
  }
  const float inv = 1.0f / sred[0];
  for (int k = tid; k < F_BINS; k += 256) {
    const float m = smag[k] * inv;
    const float pha = -gd * ((float)k * 0.125f) * PI_F;
    float sn, cs;
    sincosf(pha, &sn, &cs);
    const float dcs = (k == 0) ? 1.0f : 2.0f;
    const float sT = dcs * (1.0f / (float)T_N);
    const int p = (k & 0xF00) + ((k & 15) << 4) + ((k >> 4) & 15);
    Fc[p] = cplx{m * cs * sT, m * sn * sT};
  }
}

// ---------------- complex helpers ----------------
__device__ __forceinline__ cplx cmul(cplx a, cplx w) {
  const cplx wx = __builtin_shufflevector(w, w, 0, 0);
  const cplx wy = __builtin_shufflevector(w, w, 1, 1);
  const cplx as = __builtin_shufflevector(a, a, 1, 0);
  return cplx{-as.x, as.y} * wy + a * wx;
}
// a * conj(w)
__device__ __forceinline__ cplx cmulc(cplx a, cplx w) {
  const cplx wx = __builtin_shufflevector(w, w, 0, 0);
  const cplx wy = __builtin_shufflevector(w, w, 1, 1);
  const cplx as = __builtin_shufflevector(a, a, 1, 0);
  return cplx{as.x, -as.y} * wy + a * wx;
}
// e^{i*2pi*rev}, rev in revolutions, |rev| < 1
__device__ __forceinline__ cplx twid(float rev) {
  return cplx{__builtin_amdgcn_cosf(rev), __builtin_amdgcn_sinf(rev)};
}

// ---------------- 16-point DFT, natural order in/out, in registers ----------
template<int SGN>
__device__ __forceinline__ void dft16(cplx* __restrict__ v) {
  const float sg = (float)SGN;
  const float C1 = 0.923879532511287f, S1 = 0.382683432365090f;
  const float Hh = 0.707106781186548f;
  cplx g[16];
#pragma unroll
  for (int n2 = 0; n2 < 4; ++n2) {
    const cplx a = v[n2], b = v[4 + n2], c = v[8 + n2], d = v[12 + n2];
    const cplx t0 = a + c, t1 = a - c, t2 = b + d, t3 = b - d;
    const cplx it3 = (SGN < 0) ? cplx{t3.y, -t3.x} : cplx{-t3.y, t3.x};
    g[n2]      = t0 + t2;
    g[8 + n2]  = t0 - t2;
    g[4 + n2]  = t1 + it3;
    g[12 + n2] = t1 - it3;
  }
  g[5]  = cmul(g[5],  cplx{C1,  sg * S1});
  g[6]  = cmul(g[6],  cplx{Hh,  sg * Hh});
  g[7]  = cmul(g[7],  cplx{S1,  sg * C1});
  g[9]  = cmul(g[9],  cplx{Hh,  sg * Hh});
  g[10] = (SGN < 0) ? cplx{g[10].y, -g[10].x} : cplx{-g[10].y, g[10].x};
  g[11] = cmul(g[11], cplx{-Hh, sg * Hh});
  g[13] = cmul(g[13], cplx{S1,  sg * C1});
  g[14] = cmul(g[14], cplx{-Hh, sg * Hh});
  g[15] = cmul(g[15], cplx{-C1, -sg * S1});
#pragma unroll
  for (int k1 = 0; k1 < 4; ++k1) {
    const cplx a = g[4 * k1], b = g[4 * k1 + 1];
    const cplx c = g[4 * k1 + 2], d = g[4 * k1 + 3];
    const cplx t0 = a + c, t1 = a - c, t2 = b + d, t3 = b - d;
    const cplx it3 = (SGN < 0) ? cplx{t3.y, -t3.x} : cplx{-t3.y, t3.x};
    v[k1]      = t0 + t2;
    v[8 + k1]  = t0 - t2;
    v[4 + k1]  = t1 + it3;
    v[12 + k1] = t1 - it3;
  }
}

// full-buffer transposes (r13-r15-verified; stride 264 -> ~2-way banks)
__device__ __forceinline__ void tr_cross_fwd(cplx* __restrict__ v,
                                             cplx* __restrict__ lds, int t) {
  __syncthreads();
#pragma unroll
  for (int k = 0; k < 16; ++k) lds[k * 264 + t] = v[k];
  __syncthreads();
  const int base = (t >> 4) * 264 + (t & 15);
#pragma unroll
  for (int m = 0; m < 16; ++m) v[m] = lds[base + m * 16];
}
__device__ __forceinline__ void tr_cross_inv(cplx* __restrict__ v,
                                             cplx* __restrict__ lds, int t) {
  __syncthreads();
  const int base = (t >> 4) * 264 + (t & 15);
#pragma unroll
  for (int m = 0; m < 16; ++m) lds[base + m * 16] = v[m];
  __syncthreads();
#pragma unroll
  for (int k = 0; k < 16; ++k) v[k] = lds[k * 264 + t];
}
__device__ __forceinline__ void tr_group(cplx* __restrict__ v,
                                         cplx* __restrict__ lds, int t) {
  __syncthreads();
  const int k1 = t >> 4, s = t & 15;
  const int rowb = k1 * 264;
#pragma unroll
  for (int r = 0; r < 16; ++r)
    lds[rowb + r * 16 + ((s + r) & 15)] = v[r];
  __syncthreads();
#pragma unroll
  for (int a = 0; a < 16; ++a)
    v[a] = lds[rowb + s * 16 + ((a + s) & 15)];
}

// ---- inverse FFT body: filtered one-sided spectrum X[9] (f32) -> u ---------
__device__ __forceinline__ void inv_body(
    const cplx* __restrict__ X, const cplx* __restrict__ Fc,
    cplx* __restrict__ lds, const cplx* __restrict__ TB, cplx tcb,
    _Float16* __restrict__ upr, _Float16* __restrict__ upi, int t) {
  const int j1 = t & 15;
  const int g  = t >> 4;

  cplx v[16];
#pragma unroll
  for (int q = 0; q < 9; ++q)                  // component-wise filter (pk_mul)
    v[q] = X[q] * Fc[q * 256 + t];
#pragma unroll
  for (int q = 9; q < 16; ++q)
    v[q] = cplx{0.0f, 0.0f};                   // hilbert zero-pad (folds)

  dft16<1>(v);
#pragma unroll
  for (int k = 1; k < 16; ++k)                 // chain B' from LDS table
    v[k] = cmul(v[k], TB[k * 16 + j1]);

  tr_group(v, lds, t);                         // leading sync orders prev reads

  dft16<1>(v);
  {
    // chain C: w(m1) = tcb * TB[m1*16+k1]  (TB doubles as step table)
    v[0] = cmul(v[0], tcb);
#pragma unroll
    for (int m1 = 1; m1 < 16; ++m1) {
      const cplx w = cmul(tcb, TB[m1 * 16 + g]);
      v[m1] = cmul(v[m1], w);
    }
  }

  tr_cross_inv(v, lds, t);
  dft16<1>(v);

#pragma unroll
  for (int n1 = 0; n1 < 16; ++n1) {
    const float ir = rsqrtf(v[n1].x * v[n1].x + v[n1].y * v[n1].y + 1e-6f);
    upr[n1 * 256 + t] = (_Float16)(v[n1].x * ir);
    upi[n1 * 256 + t] = (_Float16)(v[n1].y * ir);
  }
}

// ---------------- fused: fwd (two-for-one) + unpack + 4x inverse ------------
__global__ __launch_bounds__(256) void fused_kernel(
    const float* __restrict__ x, const cplx* __restrict__ filt,
    _Float16* __restrict__ Urg, _Float16* __restrict__ Uig, int chunkbase) {
  const int cp = blockIdx.x & 31;      // channel pair: channels 2cp, 2cp+1
  const int bb = blockIdx.x >> 5;
  const int b  = chunkbase + bb;
  const int t  = threadIdx.x;
  const int j1 = t & 15;
  const int g  = t >> 4;
  __shared__ cplx lds[16 * 264];       // 33792 B full transpose buffer
  __shared__ cplx TB[256];             // twid(+a*b/256) at [a*16+b]

  TB[t] = twid((float)(g * j1) * (1.0f / 256.0f));
  const cplx tcb = twid((float)(g * j1) * (1.0f / 4096.0f));  // per-thread const

  cplx v[16];
  const float* xp0 = x + ((size_t)(b * C_N + 2 * cp)) * T_N;
  const float* xp1 = xp0 + T_N;
#pragma unroll
  for (int r = 0; r < 16; ++r)
    v[r] = cplx{xp0[r * 256 + t], xp1[r * 256 + t]};

  dft16<-1>(v);
#pragma unroll
  for (int k = 1; k < 16; ++k)                 // chain A: e^{-2pi i t k/4096}
    v[k] = cmul(v[k], twid((float)(t * k) * (-1.0f / 4096.0f)));

  tr_cross_fwd(v, lds, t);                     // leading sync covers TB too

  dft16<-1>(v);
#pragma unroll
  for (int k = 1; k < 16; ++k)                 // chain B: conj of TB
    v[k] = cmulc(v[k], TB[k * 16 + j1]);

  tr_group(v, lds, t);
  dft16<-1>(v);

  // ---- conjugate-symmetry unpack -> f32 registers (single pass) ----
  // partner: tp = (k1==0) ? ((16-j1)&15) : ((16-k1)<<4 | (15-j1));
  //          qp = (t==0) ? ((16-q)&15) : (15-q)   (self-pairs read own slot)
  const int tp = (g == 0) ? ((16 - j1) & 15)
                          : (((16 - g) << 4) | (15 - j1));
  cplx X0[9], X1[9];

  __syncthreads();                             // lds free of tr_group readers
#pragma unroll
  for (int q = 0; q < 16; ++q) lds[q * 264 + t] = v[q];
  __syncthreads();
#pragma unroll
  for (int q = 0; q < 9; ++q) {
    const int qp = (t == 0) ? ((16 - q) & 15) : (15 - q);
    const cplx Z  = v[q];
    const cplx Zp = lds[qp * 264 + tp];
    X0[q] = cplx{0.5f * (Z.x + Zp.x), 0.5f * (Z.y - Zp.y)};
    X1[q] = cplx{0.5f * (Z.y + Zp.y), 0.5f * (Zp.x - Z.x)};
  }

  // ---- 4 inverse bodies: (ch0,ch1) x (f0,f1) ----
  const int c0 = 2 * cp, c1 = 2 * cp + 1;
#pragma unroll 1
  for (int f = 0; f < NFILT; ++f) {
    const cplx* Fc = filt + f * 4096;
    const int sl = bb * 2 + f;
    _Float16* upr0 = Urg + ((size_t)sl * C_N + c0) * T_N;
    _Float16* upi0 = Uig + ((size_t)sl * C_N + c0) * T_N;
    inv_body(X0, Fc, lds, TB, tcb, upr0, upi0, t);
    _Float16* upr1 = Urg + ((size_t)sl * C_N + c1) * T_N;
    _Float16* upi1 = Uig + ((size_t)sl * C_N + c1) * T_N;
    inv_body(X1, Fc, lds, TB, tcb, upr1, upi1, t);
  }
}

// ---------------- gram via f16 MFMA -> per-tsplit partial planes ------------
__global__ __launch_bounds__(256) void gram_kernel(
    const _Float16* __restrict__ Urg, const _Float16* __restrict__ Uig,
    float* __restrict__ Gp, int slicebase) {
  const int sl = blockIdx.x / TSG;
  const int ts = blockIdx.x % TSG;
  const int tid = threadIdx.x;
  const int w = tid >> 6;
  const int lane = tid & 63;
  __shared__ _Float16 sUr[2][64 * 40], sUi[2][64 * 40];

  const int row = tid >> 2, quarter = tid & 3;
  const size_t goff = (size_t)sl * C_N * T_N + (size_t)row * T_N
                      + ts * (T_N / TSG) + quarter * 8;
  const int loff = row * 40 + quarter * 8;
  const int frow = (lane & 15) * 40 + (lane >> 4) * 8;
  const int aoff = w * 640 + frow;

  f32x4 accRr[4] = {}, accIi[4] = {}, accRi[4] = {};

  f16x8 rr = *(const f16x8*)&Urg[goff];
  f16x8 ri = *(const f16x8*)&Uig[goff];
  int cur = 0;
  for (int ks = 0; ks < NKS; ++ks) {
    *(f16x8*)&sUr[cur][loff] = rr;
    *(f16x8*)&sUi[cur][loff] = ri;
    if (ks + 1 < NKS) {
      rr = *(const f16x8*)&Urg[goff + (ks + 1) * 32];
      ri = *(const f16x8*)&Uig[goff + (ks + 1) * 32];
    }
    __syncthreads();
    const f16x8 ar = *(const f16x8*)&sUr[cur][aoff];
    const f16x8 ai = *(const f16x8*)&sUi[cur][aoff];
#pragma unroll
    for (int n = 0; n < 4; ++n) {
      const f16x8 br = *(const f16x8*)&sUr[cur][n * 640 + frow];
      const f16x8 bi = *(const f16x8*)&sUi[cur][n * 640 + frow];
      accRr[n] = __builtin_amdgcn_mfma_f32_16x16x32_f16(ar, br, accRr[n], 0, 0, 0);
      accIi[n] = __builtin_amdgcn_mfma_f32_16x16x32_f16(ai, bi, accIi[n], 0, 0, 0);
      accRi[n] = __builtin_amdgcn_mfma_f32_16x16x32_f16(ar, bi, accRi[n], 0, 0, 0);
    }
    cur ^= 1;
  }

  float* Gs = Gp + (size_t)((slicebase + sl) * TSG + ts) * 12288;
  const int r0 = w * 16 + (lane >> 4) * 4;
  const int c0 = lane & 15;
#pragma unroll
  for (int n = 0; n < 4; ++n) {
    const bool upper = (n >= w);   // strictly-below-diagonal Rr/Ii never read
#pragma unroll
    for (int e = 0; e < 4; ++e) {
      const int idx = (r0 + e) * 64 + n * 16 + c0;
      if (upper) {
        Gs[idx] = accRr[n][e];
        Gs[4096 + idx] = accIi[n][e];
      }
      Gs[8192 + idx] = accRi[n][e];
    }
  }
}

// ---------------- PLV (sums TSG partials) + scatter to feature layout -------
__global__ __launch_bounds__(256) void plv_kernel(
    const float* __restrict__ Gp, float* __restrict__ feats) {
  const int idx = blockIdx.x * 256 + threadIdx.x;
  if (idx >= B_N * NFILT * NPAIRS) return;
  const int slice = idx / NPAIRS;
  const int p = idx - slice * NPAIRS;
  const int b = slice >> 1, f = slice & 1;
  const int r = NPAIRS - 1 - p;
  int m = (int)((sqrtf((float)(8 * r + 1)) - 1.0f) * 0.5f);
  while ((m + 1) * (m + 2) / 2 <= r) ++m;
  while (m * (m + 1) / 2 > r) --m;
  const int c = 62 - m;
  const int d = 63 - (r - m * (m + 1) / 2);
  const float* Gs = Gp + (size_t)slice * TSG * 12288;
  float rr = 0, ii = 0, ri = 0, ir = 0;
#pragma unroll
  for (int ts = 0; ts < TSG; ++ts) {
    const float* P = Gs + ts * 12288;
    rr += P[c * 64 + d];
    ii += P[4096 + c * 64 + d];
    ri += P[8192 + c * 64 + d];
    ir += P[8192 + d * 64 + c];
  }
  const float cre = rr + ii;
  const float cim = ri - ir;
  const float plv = sqrtf(cre * cre + cim * cim + 1e-6f) * (1.0f / (float)T_N);
  feats[b * NFEAT + p * NFILT + f] = plv;
}

// ---------------- batch stats (training-mode BN, biased var) ----------------
__global__ __launch_bounds__(64) void stats_kernel(
    const float* __restrict__ feats, float* __restrict__ stats) {
  const int j = blockIdx.x * 64 + threadIdx.x;
  if (j >= NFEAT) return;
  float s = 0.0f;
  for (int b = 0; b < B_N; ++b) s += feats[b * NFEAT + j];
  const float mu = s * (1.0f / (float)B_N);
  float v = 0.0f;
  for (int b = 0; b < B_N; ++b) {
    const float d = feats[b * NFEAT + j] - mu;
    v += d * d;
  }
  v *= (1.0f / (float)B_N);
  stats[j] = mu;
  stats[NFEAT + j] = 1.0f / sqrtf(v + 1e-5f);
}

// ---------------- normalize + linear ----------------
__global__ __launch_bounds__(256) void out_kernel(
    const float* __restrict__ feats, const float* __restrict__ stats,
    const float* __restrict__ w, const float* __restrict__ lb,
    float* __restrict__ out) {
  const int b = blockIdx.x;
  const int tid = threadIdx.x;
  float acc0 = 0, acc1 = 0, acc2 = 0, acc3 = 0;
  for (int j = tid; j < NFEAT; j += 256) {
    const float v = (feats[b * NFEAT + j] - stats[j]) * stats[NFEAT + j];
    acc0 += v * w[0 * NFEAT + j];
    acc1 += v * w[1 * NFEAT + j];
    acc2 += v * w[2 * NFEAT + j];
    acc3 += v * w[3 * NFEAT + j];
  }
  __shared__ float red[4][256];
  red[0][tid] = acc0; red[1][tid] = acc1; red[2][tid] = acc2; red[3][tid] = acc3;
  __syncthreads();
  for (int s = 128; s > 0; s >>= 1) {
    if (tid < s) {
#pragma unroll
      for (int o = 0; o < 4; ++o) red[o][tid] += red[o][tid + s];
    }
    __syncthreads();
  }
  if (tid < 4) out[b * NOUT + tid] = red[tid][0] + lb[tid];
}

extern "C" void kernel_launch(void* const* d_in, const int* in_sizes, int n_in,
                              void* d_out, int out_size, void* d_ws, size_t ws_size,
                              hipStream_t stream) {
  const float* x  = (const float*)d_in[0];
  const float* fm = (const float*)d_in[1];
  const float* bw = (const float*)d_in[2];
  const float* sp = (const float*)d_in[3];
  const float* gd = (const float*)d_in[4];
  const float* lw = (const float*)d_in[5];
  const float* lb = (const float*)d_in[6];
  float* out = (float*)d_out;
  char* base = (char*)d_ws;

  // adaptive batch chunk: largest of {64,32,16} that fits ws
  const size_t perCB = 2 * 1048576;            // u planes only (X stays in regs)
  const size_t fixed = OFF_U + (size_t)G_BYTES + (size_t)B_N * NFEAT * 4 + 2 * NFEAT * 4;
  int CB = 64;
  if (ws_size < fixed + (size_t)64 * perCB) CB = 32;
  if (ws_size < fixed + (size_t)32 * perCB) CB = 16;
  const int nchunk = B_N / CB;

  const size_t u_bytes = (size_t)CB * 1048576;  // per component array
  cplx*     filt  = (cplx*)base;
  _Float16* Urg   = (_Float16*)(base + OFF_U);
  _Float16* Uig   = (_Float16*)(base + OFF_U + u_bytes);
  float*    Gp    = (float*)(base + OFF_U + 2 * u_bytes);
  float*    feats = (float*)(base + OFF_U + 2 * u_bytes + G_BYTES);
  float*    stats = feats + (size_t)B_N * NFEAT;

  filter_kernel<<<NFILT, 256, 0, stream>>>(fm, bw, sp, gd, filt);

  for (int chunk = 0; chunk < nchunk; ++chunk) {
    fused_kernel<<<CB * (C_N / 2), 256, 0, stream>>>(x, filt, Urg, Uig, chunk * CB);
    gram_kernel<<<CB * 2 * TSG, 256, 0, stream>>>(Urg, Uig, Gp, chunk * CB * 2);
  }

  plv_kernel<<<(B_N * NFILT * NPAIRS + 255) / 256, 256, 0, stream>>>(Gp, feats);
  stats_kernel<<<(NFEAT + 63) / 64, 64, 0, stream>>>(feats, stats);
  out_kernel<<<B_N, 256, 0, stream>>>(feats, stats, lw, lb, out);
}